// Round 11
// baseline (404.025 us; speedup 1.0000x reference)
//
#include <hip/hip_runtime.h>

// ---------------------------------------------------------------------------
// ConditionalCrossAttentionBlock: LN -> K/V proj -> RMS(Q proj) -> RoPE ->
// 16-head cross attention (LQ=4096, LKV=1024, Dh=128) -> O proj.
// R11: attn waves own 64 q rows (2 groups) sharing K/V fragments across
// groups -> LDS reads per q-row halved. KVBLK=64, LDS 64KB, grid 256.
// All R8-proven layouts (K 256B rows swz (row&15)<<4, paired-d V) unchanged.
// ---------------------------------------------------------------------------

typedef __attribute__((ext_vector_type(8))) short    short8;
typedef __attribute__((ext_vector_type(8))) unsigned short ushort8;
typedef __attribute__((ext_vector_type(4))) unsigned short ushort4v;
typedef __attribute__((ext_vector_type(4))) float    f32x4;
typedef __attribute__((ext_vector_type(16))) float   f32x16;
typedef __attribute__((ext_vector_type(4))) unsigned int uint4v;

#define DEV __device__ __forceinline__

DEV unsigned short f2bf(float f) {
  unsigned int u = __builtin_bit_cast(unsigned int, f);
  u += 0x7FFFu + ((u >> 16) & 1u);        // RNE, inputs are finite
  return (unsigned short)(u >> 16);
}
DEV float bf2f(unsigned short h) {
  return __builtin_bit_cast(float, ((unsigned int)h) << 16);
}
DEV unsigned int cvtpk_bf16(float lo, float hi) {
  unsigned int r;
  asm("v_cvt_pk_bf16_f32 %0, %1, %2" : "=v"(r) : "v"(lo), "v"(hi));
  return r;
}
DEV short8 mk8(unsigned a, unsigned b, unsigned c, unsigned d) {
  uint4v t; t.x = a; t.y = b; t.z = c; t.w = d;
  return __builtin_bit_cast(short8, t);
}

DEV void gload_lds16(const void* g, void* l) {
  __builtin_amdgcn_global_load_lds(
      (const __attribute__((address_space(1))) void*)g,
      (__attribute__((address_space(3))) void*)l, 16, 0, 0);
}

// ---------------------------------------------------------------------------
// f32 -> bf16 convert (grid-stride, float4 in / 8B out)
// ---------------------------------------------------------------------------
__global__ __launch_bounds__(256) void cvt_kernel(const float* __restrict__ in,
                                                  unsigned short* __restrict__ out,
                                                  int n4) {
  int idx = blockIdx.x * 256 + threadIdx.x;
  int stride = gridDim.x * 256;
  for (int i = idx; i < n4; i += stride) {
    float4 v = *(const float4*)(in + (size_t)i * 4);
    ushort4v o;
    o.x = f2bf(v.x); o.y = f2bf(v.y); o.z = f2bf(v.z); o.w = f2bf(v.w);
    *(ushort4v*)(out + (size_t)i * 4) = o;
  }
}

// ---------------------------------------------------------------------------
// 4-segment f32 -> bf16 convert (one launch for all weights)
// ---------------------------------------------------------------------------
__global__ __launch_bounds__(256) void cvt4_kernel(const float* __restrict__ s0,
                                                   const float* __restrict__ s1,
                                                   const float* __restrict__ s2,
                                                   const float* __restrict__ s3,
                                                   unsigned short* __restrict__ d0,
                                                   unsigned short* __restrict__ d1,
                                                   unsigned short* __restrict__ d2,
                                                   unsigned short* __restrict__ d3,
                                                   int n0, int n1, int n2, int n3) {
  const int total = n0 + n1 + n2 + n3;
  int idx = blockIdx.x * 256 + threadIdx.x;
  const int stride = gridDim.x * 256;
  for (int i = idx; i < total; i += stride) {
    int j = i;
    const float* s; unsigned short* d;
    if (j < n0) { s = s0; d = d0; }
    else if ((j -= n0) < n1) { s = s1; d = d1; }
    else if ((j -= n1) < n2) { s = s2; d = d2; }
    else { j -= n2; s = s3; d = d3; }
    float4 v = *(const float4*)(s + (size_t)j * 4);
    ushort4v o;
    o.x = f2bf(v.x); o.y = f2bf(v.y); o.z = f2bf(v.z); o.w = f2bf(v.w);
    *(ushort4v*)(d + (size_t)j * 4) = o;
  }
}

// ---------------------------------------------------------------------------
// LayerNorm over rows of 1024 (y -> yn bf16). One block per row.
// ---------------------------------------------------------------------------
__global__ __launch_bounds__(256) void ln_kernel(const float* __restrict__ y,
                                                 const float* __restrict__ w,
                                                 const float* __restrict__ b,
                                                 unsigned short* __restrict__ yn) {
  const int row = blockIdx.x;               // 2048 rows
  const int t = threadIdx.x;
  const float* yr = y + (size_t)row * 1024;
  float4 v = *(const float4*)(yr + t * 4);
  float s1 = v.x + v.y + v.z + v.w;
  float s2 = v.x * v.x + v.y * v.y + v.z * v.z + v.w * v.w;
#pragma unroll
  for (int m = 1; m < 64; m <<= 1) {
    s1 += __shfl_xor(s1, m);
    s2 += __shfl_xor(s2, m);
  }
  __shared__ float red[8];
  const int wave = t >> 6, lane = t & 63;
  if (lane == 0) { red[wave] = s1; red[4 + wave] = s2; }
  __syncthreads();
  s1 = red[0] + red[1] + red[2] + red[3];
  s2 = red[4] + red[5] + red[6] + red[7];
  const float mu = s1 * (1.0f / 1024.0f);
  const float var = s2 * (1.0f / 1024.0f) - mu * mu;
  const float rs = rsqrtf(var + 1e-6f);
  ushort4v o;
  o.x = f2bf((v.x - mu) * rs * w[t * 4 + 0] + b[t * 4 + 0]);
  o.y = f2bf((v.y - mu) * rs * w[t * 4 + 1] + b[t * 4 + 1]);
  o.z = f2bf((v.z - mu) * rs * w[t * 4 + 2] + b[t * 4 + 2]);
  o.w = f2bf((v.w - mu) * rs * w[t * 4 + 3] + b[t * 4 + 3]);
  *(ushort4v*)(yn + (size_t)row * 1024 + t * 4) = o;
}

// ---------------------------------------------------------------------------
// 128x128 GEMM (m97 structure) for the merged K/V projection.
// bias = n<nsplit ? b0[n] : b1[n-nsplit].
// ---------------------------------------------------------------------------
__global__ __launch_bounds__(256) void gemm_bt(const unsigned short* __restrict__ A,
                                               const unsigned short* __restrict__ W,
                                               const float* __restrict__ bias0,
                                               const float* __restrict__ bias1,
                                               int nsplit,
                                               unsigned short* __restrict__ Cout,
                                               int M, int N, int K) {
  __shared__ __align__(16) char sA[128 * 128];
  __shared__ __align__(16) char sB[128 * 128];
  const int tid = threadIdx.x;
  const int wave = tid >> 6, lane = tid & 63;
  const int lg = lane >> 4, l15 = lane & 15;
  const int wr = wave >> 1, wc = wave & 1;
  const int m0 = blockIdx.y * 128;
  const int n0 = blockIdx.x * 128;
  const char* Ab = (const char*)A;
  const char* Wb = (const char*)W;
  const size_t ldab = (size_t)K * 2;

  f32x4 acc[4][4] = {};

  for (int kt = 0; kt < K; kt += 64) {
#pragma unroll
    for (int i = 0; i < 4; ++i) {
      const int p = (i * 256 + tid) * 16;
      const int row = p >> 7;
      const int si = (p & 127) ^ ((row & 7) << 4);
      gload_lds16(Ab + (size_t)(m0 + row) * ldab + (size_t)kt * 2 + si, sA + p);
    }
#pragma unroll
    for (int i = 0; i < 4; ++i) {
      const int p = (i * 256 + tid) * 16;
      const int row = p >> 7;
      const int si = (p & 127) ^ ((row & 7) << 4);
      gload_lds16(Wb + (size_t)(n0 + row) * ldab + (size_t)kt * 2 + si, sB + p);
    }
    __syncthreads();
#pragma unroll
    for (int ks = 0; ks < 2; ++ks) {
      const int kb = (ks * 32 + lg * 8) * 2;
      short8 af[4], bw[4];
#pragma unroll
      for (int mf = 0; mf < 4; ++mf) {
        const int row = wr * 64 + mf * 16 + l15;
        af[mf] = *(const short8*)(sA + row * 128 + (kb ^ ((row & 7) << 4)));
      }
#pragma unroll
      for (int nf = 0; nf < 4; ++nf) {
        const int row = wc * 64 + nf * 16 + l15;
        bw[nf] = *(const short8*)(sB + row * 128 + (kb ^ ((row & 7) << 4)));
      }
#pragma unroll
      for (int mf = 0; mf < 4; ++mf)
#pragma unroll
        for (int nf = 0; nf < 4; ++nf)
          acc[mf][nf] = __builtin_amdgcn_mfma_f32_16x16x32_bf16(af[mf], bw[nf],
                                                                acc[mf][nf], 0, 0, 0);
    }
    __syncthreads();
  }

#pragma unroll
  for (int nf = 0; nf < 4; ++nf) {
    const int n = n0 + wc * 64 + nf * 16 + l15;
    const float bv = (n < nsplit) ? bias0[n] : bias1[n - nsplit];
#pragma unroll
    for (int mf = 0; mf < 4; ++mf) {
      const int mB = m0 + wr * 64 + mf * 16 + lg * 4;
#pragma unroll
      for (int r = 0; r < 4; ++r)
        Cout[(size_t)(mB + r) * N + n] = f2bf(acc[mf][nf][r] + bv);
    }
  }
}

// ---------------------------------------------------------------------------
// 256x256 8-phase pipelined GEMM (T2+T3+T4+T5).  C = A[M,K] @ W[N,K]^T + bias.
// ---------------------------------------------------------------------------
template <int EPI>
__global__ __launch_bounds__(512, 2) void gemm256(const unsigned short* __restrict__ A,
                                                  const unsigned short* __restrict__ W,
                                                  const float* __restrict__ bias,
                                                  void* __restrict__ Cout,
                                                  int M, int N, int K) {
  __shared__ __align__(16) char lds[2][4][16384];  // [buf][A0,A1,B0,B1]
  const int tid = threadIdx.x;
  const int wave = tid >> 6, lane = tid & 63;
  const int lg = lane >> 4, l15 = lane & 15;
  const int wm = wave >> 2, wn = wave & 3;

  const int nwg = gridDim.x;
  const int wgid = (blockIdx.x & 7) * (nwg >> 3) + (blockIdx.x >> 3);
  const int nbn = N >> 8;
  const int m0 = (wgid / nbn) * 256;
  const int n0 = (wgid % nbn) * 256;

  const char* Ab = (const char*)A;
  const char* Wb = (const char*)W;
  const size_t ld = (size_t)K * 2;
  const int NT = K >> 6;
  const int NI = NT >> 1;

  const int prow = tid >> 3;
  const int psw  = ((tid * 16) & 127) ^ ((prow & 7) << 4);
  const int pdst = tid * 16;
  const char* pAg = Ab + (size_t)(m0 + prow) * ld + psw;
  const char* pBg = Wb + (size_t)(n0 + prow) * ld + psw;

  f32x4 acc[8][4] = {};
  short8 af[4][2];
  short8 bf[4][2];

#define STG(BUF, HALF, ISB, TAU) do {                                         \
    const char* _g = ((ISB) ? pBg : pAg) + (size_t)(HALF) * 128 * ld +        \
                     (size_t)(TAU) * 128;                                     \
    char* _l = lds[BUF][(ISB) * 2 + (HALF)];                                  \
    gload_lds16(_g, _l + pdst);                                               \
    gload_lds16(_g + 64 * ld, _l + pdst + 8192);                              \
  } while (0)

#define LDA(BUF, H) do {                                                      \
    const char* _b = lds[BUF][wm];                                            \
    _Pragma("unroll") for (int mfl = 0; mfl < 4; ++mfl) {                     \
      const int _r = (H) * 64 + mfl * 16 + l15;                               \
      _Pragma("unroll") for (int ks = 0; ks < 2; ++ks)                        \
        af[mfl][ks] = *(const short8*)(_b + _r * 128 +                        \
                        ((ks * 64 + lg * 16) ^ ((_r & 7) << 4)));             \
    }                                                                         \
  } while (0)

#define LDB(BUF, G) do {                                                      \
    const char* _b = lds[BUF][2 + (wn >> 1)];                                 \
    _Pragma("unroll") for (int nfl = 0; nfl < 2; ++nfl) {                     \
      const int _r = (wn & 1) * 64 + (G) * 32 + nfl * 16 + l15;               \
      _Pragma("unroll") for (int ks = 0; ks < 2; ++ks)                        \
        bf[(G) * 2 + nfl][ks] = *(const short8*)(_b + _r * 128 +              \
                        ((ks * 64 + lg * 16) ^ ((_r & 7) << 4)));             \
    }                                                                         \
  } while (0)

#define MFMA_Q(H, G) do {                                                     \
    __builtin_amdgcn_s_setprio(1);                                            \
    _Pragma("unroll") for (int ks = 0; ks < 2; ++ks)                          \
    _Pragma("unroll") for (int mfl = 0; mfl < 4; ++mfl)                       \
    _Pragma("unroll") for (int nfl = 0; nfl < 2; ++nfl)                       \
      acc[(H) * 4 + mfl][(G) * 2 + nfl] =                                     \
        __builtin_amdgcn_mfma_f32_16x16x32_bf16(af[mfl][ks],                  \
            bf[(G) * 2 + nfl][ks], acc[(H) * 4 + mfl][(G) * 2 + nfl], 0,0,0); \
    __builtin_amdgcn_s_setprio(0);                                            \
  } while (0)

#define BAR() __builtin_amdgcn_s_barrier()
#define LGKM0() do { asm volatile("s_waitcnt lgkmcnt(0)" ::: "memory");       \
    __builtin_amdgcn_sched_barrier(0); } while (0)
#define VM4() asm volatile("s_waitcnt vmcnt(4)" ::: "memory")
#define VM0() asm volatile("s_waitcnt vmcnt(0)" ::: "memory")

  STG(0, 0, 0, 0); STG(0, 1, 0, 0); STG(0, 0, 1, 0); STG(0, 1, 1, 0);
  STG(1, 0, 1, 1); STG(1, 1, 1, 1);
  VM4(); BAR();

  for (int t = 0; t < NI - 1; ++t) {
    const int t2 = 2 * t;
    LDA(0, 0); LDB(0, 0); STG(1, 0, 0, t2 + 1);
    BAR(); LGKM0(); MFMA_Q(0, 0); BAR();
    LDB(0, 1); STG(1, 1, 0, t2 + 1);
    BAR(); LGKM0(); MFMA_Q(0, 1); BAR();
    LDA(0, 1); STG(0, 0, 1, t2 + 2);
    BAR(); LGKM0(); MFMA_Q(1, 1); BAR();
    STG(0, 1, 1, t2 + 2);
    BAR(); MFMA_Q(1, 0); VM4(); BAR();
    LDA(1, 0); LDB(1, 0); STG(0, 0, 0, t2 + 2);
    BAR(); LGKM0(); MFMA_Q(0, 0); BAR();
    LDB(1, 1); STG(0, 1, 0, t2 + 2);
    BAR(); LGKM0(); MFMA_Q(0, 1); BAR();
    LDA(1, 1); STG(1, 0, 1, t2 + 3);
    BAR(); LGKM0(); MFMA_Q(1, 1); BAR();
    STG(1, 1, 1, t2 + 3);
    BAR(); MFMA_Q(1, 0); VM4(); BAR();
  }

  LDA(0, 0); LDB(0, 0); STG(1, 0, 0, NT - 1);
  BAR(); LGKM0(); MFMA_Q(0, 0); BAR();
  LDB(0, 1); STG(1, 1, 0, NT - 1);
  BAR(); LGKM0(); MFMA_Q(0, 1); BAR();
  LDA(0, 1);
  BAR(); LGKM0(); MFMA_Q(1, 1); BAR();
  BAR(); MFMA_Q(1, 0); VM0(); BAR();
  LDA(1, 0); LDB(1, 0); LGKM0(); MFMA_Q(0, 0);
  LDB(1, 1); LGKM0(); MFMA_Q(0, 1);
  LDA(1, 1); LGKM0(); MFMA_Q(1, 1);
  MFMA_Q(1, 0);

#undef STG
#undef LDA
#undef LDB
#undef MFMA_Q
#undef BAR
#undef LGKM0
#undef VM4
#undef VM0

#pragma unroll
  for (int nf = 0; nf < 4; ++nf) {
    const int n = n0 + wn * 64 + nf * 16 + l15;
    const float bv = bias[n];
#pragma unroll
    for (int mf = 0; mf < 8; ++mf) {
      const int mB = m0 + wm * 128 + mf * 16 + lg * 4;
#pragma unroll
      for (int r = 0; r < 4; ++r) {
        const float v = acc[mf][nf][r] + bv;
        if constexpr (EPI == 0)
          ((unsigned short*)Cout)[(size_t)(mB + r) * N + n] = f2bf(v);
        else
          ((float*)Cout)[(size_t)(mB + r) * N + n] = v;
      }
    }
  }
}

// ---------------------------------------------------------------------------
// Fused RMSNorm (over full 2048 row) + RoPE + head-major relayout.
// in: (B*L, ldin) bf16 (first 2048 cols used). out: (B,H,L,128) bf16 * scale.
// ---------------------------------------------------------------------------
__global__ __launch_bounds__(256) void rmsrope_kernel(const unsigned short* __restrict__ in,
                                                      const float* __restrict__ w,
                                                      const float* __restrict__ cs,
                                                      const float* __restrict__ sn,
                                                      unsigned short* __restrict__ out,
                                                      int L, int ldin, float scale) {
  const int row = blockIdx.x;              // B*L
  const int t = threadIdx.x;
  __shared__ __align__(16) unsigned short srow[2048];
  __shared__ float red[4];
  const unsigned short* ir = in + (size_t)row * ldin;
  ushort8 v = *(const ushort8*)(ir + t * 8);
  float vals[8];
  float ss = 0.f;
#pragma unroll
  for (int j = 0; j < 8; ++j) { vals[j] = bf2f(v[j]); ss += vals[j] * vals[j]; }
  *(ushort8*)(srow + t * 8) = v;
#pragma unroll
  for (int m = 1; m < 64; m <<= 1) ss += __shfl_xor(ss, m);
  const int wave = t >> 6, lane = t & 63;
  if (lane == 0) red[wave] = ss;
  __syncthreads();
  const float tot = red[0] + red[1] + red[2] + red[3];
  const float rms = rsqrtf(tot * (1.0f / 2048.0f) + 1e-6f);

  const int n0 = t * 8;
  const int d0 = n0 & 127;
  const int hh = n0 >> 7;
  const float sign = (d0 < 64) ? -1.0f : 1.0f;
  const float* cb = cs + (size_t)row * 128 + d0;
  const float* sb = sn + (size_t)row * 128 + d0;
  ushort8 po = *(const ushort8*)(srow + (n0 ^ 64));
  ushort8 ou;
#pragma unroll
  for (int j = 0; j < 8; ++j) {
    const float self = vals[j] * rms * w[n0 + j];
    const float part = bf2f(po[j]) * rms * w[(n0 ^ 64) + j];
    ou[j] = f2bf((self * cb[j] + sign * part * sb[j]) * scale);
  }
  const int b = row / L, l = row - (row / L) * L;
  *(ushort8*)(out + (((size_t)(b * 16 + hh)) * L + l) * 128 + d0) = ou;
}

// ---------------------------------------------------------------------------
// V transpose: vpre (B, LKV, ldv) bf16 (128 cols per head) -> vt (B,H,128,LKV).
// ---------------------------------------------------------------------------
__global__ __launch_bounds__(256) void vtrans_kernel(const unsigned short* __restrict__ vpre,
                                                     unsigned short* __restrict__ vt,
                                                     int ldv) {
  const int bid = blockIdx.x;              // 32 bh * 16 kv tiles = 512
  const int kt = bid & 15, bh = bid >> 4;
  const int h = bh & 15, b = bh >> 4;
  __shared__ unsigned short lt[64][130];
  const int t = threadIdx.x;
  const int i0 = t >> 4, c0 = (t & 15) * 8;
  const unsigned short* src = vpre + ((size_t)(b * 1024 + kt * 64)) * ldv + h * 128;
#pragma unroll
  for (int ii = 0; ii < 4; ++ii) {
    const int i = i0 + ii * 16;
    ushort8 v = *(const ushort8*)(src + (size_t)i * ldv + c0);
#pragma unroll
    for (int j = 0; j < 8; ++j) lt[i][c0 + j] = v[j];
  }
  __syncthreads();
  const int d0 = t >> 3, j0 = (t & 7) * 8;
  unsigned short* dst = vt + (size_t)bh * 128 * 1024 + kt * 64;
#pragma unroll
  for (int dd = 0; dd < 4; ++dd) {
    const int d = d0 + dd * 32;
    ushort8 o;
#pragma unroll
    for (int jj = 0; jj < 8; ++jj) o[jj] = lt[j0 + jj][d];
    *(ushort8*)(dst + (size_t)d * 1024 + j0) = o;
  }
}

// ---------------------------------------------------------------------------
// Flash cross-attention, R11: 8 waves x 64 q rows (2 groups of 32), KVBLK=64.
// Swapped QK^T 32x32x16; K/V fragments shared across the 2 q-groups (one
// ds_read feeds 2 MFMAs) -> LDS reads per q-row halved vs R10.
// K: [kv][128d] 256B rows swz (row&15)<<4; V paired-d rows (R8 layouts).
// In-reg P via cvt_pk + shfl_xor(32); denominators via VALU adds.
// ---------------------------------------------------------------------------
__global__ __launch_bounds__(512, 2) void attn_kernel(const unsigned short* __restrict__ q,
                                                      const unsigned short* __restrict__ k,
                                                      const unsigned short* __restrict__ vt,
                                                      unsigned short* __restrict__ ao) {
  __shared__ __align__(16) char sK[2][64 * 256];    // [buf][kv 64][128 d]
  __shared__ __align__(16) char sV[2][64 * 256];    // [buf] paired-d

  // XCD-grouped swizzle: 4 heads (all their q-tiles) per XCD.
  const int bid0 = blockIdx.x;                      // 256 = 32 bh * 8 qtiles
  const int bid = (bid0 & 7) * 32 + (bid0 >> 3);
  const int qt = bid & 7, bh = bid >> 3;
  const int tid = threadIdx.x;
  const int wave = tid >> 6, lane = tid & 63;
  const int l31 = lane & 31, hi = lane >> 5;
  const bool hib = (hi != 0);

  const unsigned short* qbase = q + (((size_t)bh * 4096) + qt * 512 + wave * 64) * 128;
  const char* kbase = (const char*)(k + (size_t)bh * 1024 * 128);
  const char* vbase = (const char*)(vt + (size_t)bh * 128 * 1024);

  // Q fragments for 2 groups: col=q=g*32+l31, k(d) = step*16 + hi*8 + j
  short8 qb[2][8];
#pragma unroll
  for (int g = 0; g < 2; ++g)
#pragma unroll
    for (int step = 0; step < 8; ++step)
      qb[g][step] = *(const short8*)(qbase + (size_t)(g * 32 + l31) * 128 + step * 16 + hi * 8);

  f32x16 o[2][4] = {};     // o[g][dt]: O[q=g*32+crow(r,hi)][d=dt*32+l31]
  float lsum[2] = {0.f, 0.f};
  short8 frA[2], frB[2];   // P fragments per group (kstep 0 / 1)

// stage one 64-kv tile into buffer BUF (identical to R8)
#define STAGE_KV(BUF, KV0) do {                                              \
    _Pragma("unroll")                                                        \
    for (int i = 0; i < 2; ++i) {                                            \
      const int p = (i * 512 + tid) * 16;                                    \
      const int row = p >> 8;                                                \
      const int si = (p & 255) ^ ((row & 15) << 4);                          \
      gload_lds16(kbase + (size_t)((KV0) + row) * 256 + si, sK[BUF] + p);    \
    }                                                                        \
    _Pragma("unroll")                                                        \
    for (int i = 0; i < 2; ++i) {                                            \
      const int p = (i * 512 + tid) * 16;                                    \
      const int row = p >> 8;                                                \
      const int si = (p & 255) ^ ((row & 15) << 4);                          \
      const int d = 2 * row + (si >> 7);                                     \
      gload_lds16(vbase + (size_t)d * 2048 + (KV0) * 2 + (si & 127),         \
                  sV[BUF] + p);                                              \
    }                                                                        \
  } while (0)

// exp2 + pack + cross-half exchange for group G from scores SS (in place)
#define SM(SS, G) do {                                                       \
    float p_[16];                                                            \
    _Pragma("unroll") for (int r = 0; r < 16; ++r) p_[r] = exp2f((SS)[r]);   \
    lsum[G] += (((p_[0]+p_[1])+(p_[2]+p_[3])) + ((p_[4]+p_[5])+(p_[6]+p_[7])))\
             + (((p_[8]+p_[9])+(p_[10]+p_[11])) + ((p_[12]+p_[13])+(p_[14]+p_[15])));\
    const unsigned w0 = cvtpk_bf16(p_[0], p_[1]),  w1 = cvtpk_bf16(p_[2], p_[3]), \
                   w2 = cvtpk_bf16(p_[4], p_[5]),  w3 = cvtpk_bf16(p_[6], p_[7]), \
                   w4 = cvtpk_bf16(p_[8], p_[9]),  w5 = cvtpk_bf16(p_[10], p_[11]),\
                   w6 = cvtpk_bf16(p_[12], p_[13]),w7 = cvtpk_bf16(p_[14], p_[15]);\
    const unsigned x0 = (unsigned)__shfl_xor((int)(hib ? w0 : w2), 32);      \
    const unsigned x1 = (unsigned)__shfl_xor((int)(hib ? w1 : w3), 32);      \
    const unsigned x2 = (unsigned)__shfl_xor((int)(hib ? w4 : w6), 32);      \
    const unsigned x3 = (unsigned)__shfl_xor((int)(hib ? w5 : w7), 32);      \
    frA[G] = mk8(hib ? x0 : w0, hib ? x1 : w1, hib ? w2 : x0, hib ? w3 : x1);\
    frB[G] = mk8(hib ? x2 : w4, hib ? x3 : w5, hib ? w6 : x2, hib ? w7 : x3);\
  } while (0)

// one 32-kv half H of the 64-kv tile: shared-kf QK (both groups), softmax,
// shared-vf PV (both groups).
#define HALF(K, V, H) do {                                                   \
    f32x16 s0 = {}, s1 = {};                                                 \
    const int ksw = (l31 & 15) << 4;                                         \
    _Pragma("unroll") for (int step = 0; step < 8; ++step) {                 \
      const int cb2 = step * 32 + hi * 16;                                   \
      short8 kf = *(const short8*)((K) + ((H) * 32 + l31) * 256 + (cb2 ^ ksw));\
      s0 = __builtin_amdgcn_mfma_f32_32x32x16_bf16(kf, qb[0][step], s0, 0,0,0);\
      s1 = __builtin_amdgcn_mfma_f32_32x32x16_bf16(kf, qb[1][step], s1, 0,0,0);\
    }                                                                        \
    SM(s0, 0);                                                               \
    SM(s1, 1);                                                               \
    _Pragma("unroll") for (int kstep = 0; kstep < 2; ++kstep) {              \
      const int colb = (H) * 64 + kstep * 32 + hi * 16;                      \
      _Pragma("unroll") for (int dt = 0; dt < 4; ++dt) {                     \
        const int vrow = dt * 16 + (l31 >> 1);                               \
        const int inner = (l31 & 1) * 128 + colb;                            \
        short8 vf = *(const short8*)((V) + vrow * 256 +                      \
                                     (inner ^ ((vrow & 15) << 4)));          \
        o[0][dt] = __builtin_amdgcn_mfma_f32_32x32x16_bf16(                  \
            kstep ? frB[0] : frA[0], vf, o[0][dt], 0, 0, 0);                 \
        o[1][dt] = __builtin_amdgcn_mfma_f32_32x32x16_bf16(                  \
            kstep ? frB[1] : frA[1], vf, o[1][dt], 0, 0, 0);                 \
      }                                                                      \
    }                                                                        \
  } while (0)

#define TILE(BUF) do {                                                       \
    HALF(sK[BUF], sV[BUF], 0);                                               \
    HALF(sK[BUF], sV[BUF], 1);                                               \
  } while (0)

  STAGE_KV(0, 0);
  __syncthreads();

#pragma unroll 1
  for (int kt2 = 0; kt2 < 8; ++kt2) {
    STAGE_KV(1, (2 * kt2 + 1) * 64);     // prefetch odd tile into buf1
    TILE(0);
    __syncthreads();
    if (kt2 < 7) STAGE_KV(0, (2 * kt2 + 2) * 64);  // prefetch even tile
    TILE(1);
    __syncthreads();
  }
#undef STAGE_KV
#undef SM
#undef HALF
#undef TILE

  // ---- epilogue: per-group denom = own half + partner; redistribute ----
  float linv[2];
#pragma unroll
  for (int g = 0; g < 2; ++g) {
    float t = lsum[g] + __shfl_xor(lsum[g], 32);
    linv[g] = 1.0f / t;
  }
  const int b = bh >> 4, h = bh & 15;
#pragma unroll
  for (int g = 0; g < 2; ++g) {
#pragma unroll
    for (int r = 0; r < 16; ++r) {
      const int crow = (r & 3) + 8 * (r >> 2) + 4 * hi;
      const float inv = __shfl(linv[g], crow);   // lane crow holds denom
      const int qg = qt * 512 + wave * 64 + g * 32 + crow;
      const size_t orow = ((size_t)b * 4096 + qg) * 2048 + h * 128;
#pragma unroll
      for (int dt = 0; dt < 4; ++dt)
        ao[orow + dt * 32 + l31] = f2bf(o[g][dt][r] * inv);
    }
  }
}

// ---------------------------------------------------------------------------
extern "C" void kernel_launch(void* const* d_in, const int* in_sizes, int n_in,
                              void* d_out, int out_size, void* d_ws, size_t ws_size,
                              hipStream_t stream) {
  (void)in_sizes; (void)n_in; (void)out_size; (void)ws_size;
  const float* x      = (const float*)d_in[0];
  const float* y      = (const float*)d_in[1];
  const float* x_cos  = (const float*)d_in[2];
  const float* x_sin  = (const float*)d_in[3];
  const float* y_cos  = (const float*)d_in[4];
  const float* y_sin  = (const float*)d_in[5];
  const float* Wq     = (const float*)d_in[6];
  const float* bq     = (const float*)d_in[7];
  const float* Wk     = (const float*)d_in[8];
  const float* bk     = (const float*)d_in[9];
  const float* Wv     = (const float*)d_in[10];
  const float* bv     = (const float*)d_in[11];
  const float* Wo     = (const float*)d_in[12];
  const float* bo     = (const float*)d_in[13];
  const float* rmsq_w = (const float*)d_in[14];
  const float* rmsk_w = (const float*)d_in[15];
  const float* ln_w   = (const float*)d_in[16];
  const float* ln_b   = (const float*)d_in[17];

  char* ws = (char*)d_ws;
  unsigned short* xb    = (unsigned short*)(ws + 0);           // 33,554,432
  unsigned short* Wqb   = (unsigned short*)(ws + 33554432);    //  8,388,608
  unsigned short* Wkb   = (unsigned short*)(ws + 41943040);    //  4,194,304 (contiguous with Wvb)
  unsigned short* Wvb   = (unsigned short*)(ws + 46137344);    //  4,194,304
  unsigned short* Wob   = (unsigned short*)(ws + 50331648);    //  8,388,608
  unsigned short* ynb   = (unsigned short*)(ws + 58720256);    //  4,194,304
  unsigned short* kvpre = (unsigned short*)(ws + 62914560);    // 16,777,216 (2048 x 4096, aliased by qpre later)
  unsigned short* qpre  = (unsigned short*)(ws + 62914560);    // 33,554,432
  unsigned short* qr    = (unsigned short*)(ws + 96468992);    // 33,554,432
  unsigned short* kr    = (unsigned short*)(ws + 130023424);   //  8,388,608
  unsigned short* vt    = (unsigned short*)(ws + 138412032);   //  8,388,608
  unsigned short* ao    = xb;

  const float qscale = 1.4426950408889634f * 0.08838834764831843f; // log2e/sqrt(128)

  cvt_kernel<<<2048, 256, 0, stream>>>(x, xb, (2 * 4096 * 2048) / 4);
  cvt4_kernel<<<2048, 256, 0, stream>>>(Wq, Wk, Wv, Wo, Wqb, Wkb, Wvb, Wob,
                                        (2048 * 2048) / 4, (2048 * 1024) / 4,
                                        (2048 * 1024) / 4, (2048 * 2048) / 4);
  ln_kernel<<<2048, 256, 0, stream>>>(y, ln_w, ln_b, ynb);

  // merged K+V projection: C[2048, 4096] = yn @ [Wk;Wv]^T (+bk|bv)
  dim3 gKV(32, 16);
  gemm_bt<<<gKV, 256, 0, stream>>>(ynb, Wkb, bk, bv, 2048, kvpre, 2048, 4096, 1024);
  rmsrope_kernel<<<2048, 256, 0, stream>>>(kvpre, rmsk_w, y_cos, y_sin, kr, 1024, 4096, 1.0f);
  vtrans_kernel<<<512, 256, 0, stream>>>(kvpre + 2048, vt, 4096);

  gemm256<0><<<256, 512, 0, stream>>>(xb, Wqb, bq, qpre, 8192, 2048, 2048);
  rmsrope_kernel<<<8192, 256, 0, stream>>>(qpre, rmsq_w, x_cos, x_sin, qr, 4096, 2048, qscale);

  attn_kernel<<<256, 512, 0, stream>>>(qr, kr, vt, ao);

  gemm256<1><<<256, 512, 0, stream>>>(ao, Wob, bo, (float*)d_out, 8192, 2048, 2048);
}

// Round 12
// 313.107 us; speedup vs baseline: 1.2904x; 1.2904x over previous
//
#include <hip/hip_runtime.h>

// ---------------------------------------------------------------------------
// ConditionalCrossAttentionBlock: LN -> K/V proj -> RMS(Q proj) -> RoPE ->
// 16-head cross attention (LQ=4096, LKV=1024, Dh=128) -> O proj.
// R12: attn reverted to R10 (proven 92.7us: KVBLK=128, 2x2 subtiles, no
// spill). K/V projection moved onto gemm256 (dual-bias epilogue, grid 128).
// R11's dual-group attn spilled (3rd spill incident) — direction closed.
// ---------------------------------------------------------------------------

typedef __attribute__((ext_vector_type(8))) short    short8;
typedef __attribute__((ext_vector_type(8))) unsigned short ushort8;
typedef __attribute__((ext_vector_type(4))) unsigned short ushort4v;
typedef __attribute__((ext_vector_type(4))) float    f32x4;
typedef __attribute__((ext_vector_type(16))) float   f32x16;
typedef __attribute__((ext_vector_type(4))) unsigned int uint4v;

#define DEV __device__ __forceinline__

DEV unsigned short f2bf(float f) {
  unsigned int u = __builtin_bit_cast(unsigned int, f);
  u += 0x7FFFu + ((u >> 16) & 1u);        // RNE, inputs are finite
  return (unsigned short)(u >> 16);
}
DEV float bf2f(unsigned short h) {
  return __builtin_bit_cast(float, ((unsigned int)h) << 16);
}
DEV unsigned int cvtpk_bf16(float lo, float hi) {
  unsigned int r;
  asm("v_cvt_pk_bf16_f32 %0, %1, %2" : "=v"(r) : "v"(lo), "v"(hi));
  return r;
}
DEV short8 mk8(unsigned a, unsigned b, unsigned c, unsigned d) {
  uint4v t; t.x = a; t.y = b; t.z = c; t.w = d;
  return __builtin_bit_cast(short8, t);
}

DEV void gload_lds16(const void* g, void* l) {
  __builtin_amdgcn_global_load_lds(
      (const __attribute__((address_space(1))) void*)g,
      (__attribute__((address_space(3))) void*)l, 16, 0, 0);
}

// ---------------------------------------------------------------------------
// f32 -> bf16 convert (grid-stride, float4 in / 8B out)
// ---------------------------------------------------------------------------
__global__ __launch_bounds__(256) void cvt_kernel(const float* __restrict__ in,
                                                  unsigned short* __restrict__ out,
                                                  int n4) {
  int idx = blockIdx.x * 256 + threadIdx.x;
  int stride = gridDim.x * 256;
  for (int i = idx; i < n4; i += stride) {
    float4 v = *(const float4*)(in + (size_t)i * 4);
    ushort4v o;
    o.x = f2bf(v.x); o.y = f2bf(v.y); o.z = f2bf(v.z); o.w = f2bf(v.w);
    *(ushort4v*)(out + (size_t)i * 4) = o;
  }
}

// ---------------------------------------------------------------------------
// 4-segment f32 -> bf16 convert (one launch for all weights)
// ---------------------------------------------------------------------------
__global__ __launch_bounds__(256) void cvt4_kernel(const float* __restrict__ s0,
                                                   const float* __restrict__ s1,
                                                   const float* __restrict__ s2,
                                                   const float* __restrict__ s3,
                                                   unsigned short* __restrict__ d0,
                                                   unsigned short* __restrict__ d1,
                                                   unsigned short* __restrict__ d2,
                                                   unsigned short* __restrict__ d3,
                                                   int n0, int n1, int n2, int n3) {
  const int total = n0 + n1 + n2 + n3;
  int idx = blockIdx.x * 256 + threadIdx.x;
  const int stride = gridDim.x * 256;
  for (int i = idx; i < total; i += stride) {
    int j = i;
    const float* s; unsigned short* d;
    if (j < n0) { s = s0; d = d0; }
    else if ((j -= n0) < n1) { s = s1; d = d1; }
    else if ((j -= n1) < n2) { s = s2; d = d2; }
    else { j -= n2; s = s3; d = d3; }
    float4 v = *(const float4*)(s + (size_t)j * 4);
    ushort4v o;
    o.x = f2bf(v.x); o.y = f2bf(v.y); o.z = f2bf(v.z); o.w = f2bf(v.w);
    *(ushort4v*)(d + (size_t)j * 4) = o;
  }
}

// ---------------------------------------------------------------------------
// LayerNorm over rows of 1024 (y -> yn bf16). One block per row.
// ---------------------------------------------------------------------------
__global__ __launch_bounds__(256) void ln_kernel(const float* __restrict__ y,
                                                 const float* __restrict__ w,
                                                 const float* __restrict__ b,
                                                 unsigned short* __restrict__ yn) {
  const int row = blockIdx.x;               // 2048 rows
  const int t = threadIdx.x;
  const float* yr = y + (size_t)row * 1024;
  float4 v = *(const float4*)(yr + t * 4);
  float s1 = v.x + v.y + v.z + v.w;
  float s2 = v.x * v.x + v.y * v.y + v.z * v.z + v.w * v.w;
#pragma unroll
  for (int m = 1; m < 64; m <<= 1) {
    s1 += __shfl_xor(s1, m);
    s2 += __shfl_xor(s2, m);
  }
  __shared__ float red[8];
  const int wave = t >> 6, lane = t & 63;
  if (lane == 0) { red[wave] = s1; red[4 + wave] = s2; }
  __syncthreads();
  s1 = red[0] + red[1] + red[2] + red[3];
  s2 = red[4] + red[5] + red[6] + red[7];
  const float mu = s1 * (1.0f / 1024.0f);
  const float var = s2 * (1.0f / 1024.0f) - mu * mu;
  const float rs = rsqrtf(var + 1e-6f);
  ushort4v o;
  o.x = f2bf((v.x - mu) * rs * w[t * 4 + 0] + b[t * 4 + 0]);
  o.y = f2bf((v.y - mu) * rs * w[t * 4 + 1] + b[t * 4 + 1]);
  o.z = f2bf((v.z - mu) * rs * w[t * 4 + 2] + b[t * 4 + 2]);
  o.w = f2bf((v.w - mu) * rs * w[t * 4 + 3] + b[t * 4 + 3]);
  *(ushort4v*)(yn + (size_t)row * 1024 + t * 4) = o;
}

// ---------------------------------------------------------------------------
// 256x256 8-phase pipelined GEMM (T2+T3+T4+T5).  C = A[M,K] @ W[N,K]^T + bias.
// bias = n<nsplit ? bias0[n] : bias1[n-nsplit]  (nsplit 256-aligned ->
// block-uniform select; pass nsplit=N for single-bias use).
// EPI==0: bf16 out, EPI==1: f32 out.
// ---------------------------------------------------------------------------
template <int EPI>
__global__ __launch_bounds__(512, 2) void gemm256(const unsigned short* __restrict__ A,
                                                  const unsigned short* __restrict__ W,
                                                  const float* __restrict__ bias0,
                                                  const float* __restrict__ bias1,
                                                  int nsplit,
                                                  void* __restrict__ Cout,
                                                  int M, int N, int K) {
  __shared__ __align__(16) char lds[2][4][16384];  // [buf][A0,A1,B0,B1]
  const int tid = threadIdx.x;
  const int wave = tid >> 6, lane = tid & 63;
  const int lg = lane >> 4, l15 = lane & 15;
  const int wm = wave >> 2, wn = wave & 3;

  const int nwg = gridDim.x;
  const int wgid = (blockIdx.x & 7) * (nwg >> 3) + (blockIdx.x >> 3);
  const int nbn = N >> 8;
  const int m0 = (wgid / nbn) * 256;
  const int n0 = (wgid % nbn) * 256;

  const char* Ab = (const char*)A;
  const char* Wb = (const char*)W;
  const size_t ld = (size_t)K * 2;
  const int NT = K >> 6;
  const int NI = NT >> 1;

  const int prow = tid >> 3;
  const int psw  = ((tid * 16) & 127) ^ ((prow & 7) << 4);
  const int pdst = tid * 16;
  const char* pAg = Ab + (size_t)(m0 + prow) * ld + psw;
  const char* pBg = Wb + (size_t)(n0 + prow) * ld + psw;

  f32x4 acc[8][4] = {};
  short8 af[4][2];
  short8 bf[4][2];

#define STG(BUF, HALF, ISB, TAU) do {                                         \
    const char* _g = ((ISB) ? pBg : pAg) + (size_t)(HALF) * 128 * ld +        \
                     (size_t)(TAU) * 128;                                     \
    char* _l = lds[BUF][(ISB) * 2 + (HALF)];                                  \
    gload_lds16(_g, _l + pdst);                                               \
    gload_lds16(_g + 64 * ld, _l + pdst + 8192);                              \
  } while (0)

#define LDA(BUF, H) do {                                                      \
    const char* _b = lds[BUF][wm];                                            \
    _Pragma("unroll") for (int mfl = 0; mfl < 4; ++mfl) {                     \
      const int _r = (H) * 64 + mfl * 16 + l15;                               \
      _Pragma("unroll") for (int ks = 0; ks < 2; ++ks)                        \
        af[mfl][ks] = *(const short8*)(_b + _r * 128 +                        \
                        ((ks * 64 + lg * 16) ^ ((_r & 7) << 4)));             \
    }                                                                         \
  } while (0)

#define LDB(BUF, G) do {                                                      \
    const char* _b = lds[BUF][2 + (wn >> 1)];                                 \
    _Pragma("unroll") for (int nfl = 0; nfl < 2; ++nfl) {                     \
      const int _r = (wn & 1) * 64 + (G) * 32 + nfl * 16 + l15;               \
      _Pragma("unroll") for (int ks = 0; ks < 2; ++ks)                        \
        bf[(G) * 2 + nfl][ks] = *(const short8*)(_b + _r * 128 +              \
                        ((ks * 64 + lg * 16) ^ ((_r & 7) << 4)));             \
    }                                                                         \
  } while (0)

#define MFMA_Q(H, G) do {                                                     \
    __builtin_amdgcn_s_setprio(1);                                            \
    _Pragma("unroll") for (int ks = 0; ks < 2; ++ks)                          \
    _Pragma("unroll") for (int mfl = 0; mfl < 4; ++mfl)                       \
    _Pragma("unroll") for (int nfl = 0; nfl < 2; ++nfl)                       \
      acc[(H) * 4 + mfl][(G) * 2 + nfl] =                                     \
        __builtin_amdgcn_mfma_f32_16x16x32_bf16(af[mfl][ks],                  \
            bf[(G) * 2 + nfl][ks], acc[(H) * 4 + mfl][(G) * 2 + nfl], 0,0,0); \
    __builtin_amdgcn_s_setprio(0);                                            \
  } while (0)

#define BAR() __builtin_amdgcn_s_barrier()
#define LGKM0() do { asm volatile("s_waitcnt lgkmcnt(0)" ::: "memory");       \
    __builtin_amdgcn_sched_barrier(0); } while (0)
#define VM4() asm volatile("s_waitcnt vmcnt(4)" ::: "memory")
#define VM0() asm volatile("s_waitcnt vmcnt(0)" ::: "memory")

  STG(0, 0, 0, 0); STG(0, 1, 0, 0); STG(0, 0, 1, 0); STG(0, 1, 1, 0);
  STG(1, 0, 1, 1); STG(1, 1, 1, 1);
  VM4(); BAR();

  for (int t = 0; t < NI - 1; ++t) {
    const int t2 = 2 * t;
    LDA(0, 0); LDB(0, 0); STG(1, 0, 0, t2 + 1);
    BAR(); LGKM0(); MFMA_Q(0, 0); BAR();
    LDB(0, 1); STG(1, 1, 0, t2 + 1);
    BAR(); LGKM0(); MFMA_Q(0, 1); BAR();
    LDA(0, 1); STG(0, 0, 1, t2 + 2);
    BAR(); LGKM0(); MFMA_Q(1, 1); BAR();
    STG(0, 1, 1, t2 + 2);
    BAR(); MFMA_Q(1, 0); VM4(); BAR();
    LDA(1, 0); LDB(1, 0); STG(0, 0, 0, t2 + 2);
    BAR(); LGKM0(); MFMA_Q(0, 0); BAR();
    LDB(1, 1); STG(0, 1, 0, t2 + 2);
    BAR(); LGKM0(); MFMA_Q(0, 1); BAR();
    LDA(1, 1); STG(1, 0, 1, t2 + 3);
    BAR(); LGKM0(); MFMA_Q(1, 1); BAR();
    STG(1, 1, 1, t2 + 3);
    BAR(); MFMA_Q(1, 0); VM4(); BAR();
  }

  LDA(0, 0); LDB(0, 0); STG(1, 0, 0, NT - 1);
  BAR(); LGKM0(); MFMA_Q(0, 0); BAR();
  LDB(0, 1); STG(1, 1, 0, NT - 1);
  BAR(); LGKM0(); MFMA_Q(0, 1); BAR();
  LDA(0, 1);
  BAR(); LGKM0(); MFMA_Q(1, 1); BAR();
  BAR(); MFMA_Q(1, 0); VM0(); BAR();
  LDA(1, 0); LDB(1, 0); LGKM0(); MFMA_Q(0, 0);
  LDB(1, 1); LGKM0(); MFMA_Q(0, 1);
  LDA(1, 1); LGKM0(); MFMA_Q(1, 1);
  MFMA_Q(1, 0);

#undef STG
#undef LDA
#undef LDB
#undef MFMA_Q
#undef BAR
#undef LGKM0
#undef VM4
#undef VM0

#pragma unroll
  for (int nf = 0; nf < 4; ++nf) {
    const int n = n0 + wn * 64 + nf * 16 + l15;
    const float bv = (n < nsplit) ? bias0[n] : bias1[n - nsplit];
#pragma unroll
    for (int mf = 0; mf < 8; ++mf) {
      const int mB = m0 + wm * 128 + mf * 16 + lg * 4;
#pragma unroll
      for (int r = 0; r < 4; ++r) {
        const float v = acc[mf][nf][r] + bv;
        if constexpr (EPI == 0)
          ((unsigned short*)Cout)[(size_t)(mB + r) * N + n] = f2bf(v);
        else
          ((float*)Cout)[(size_t)(mB + r) * N + n] = v;
      }
    }
  }
}

// ---------------------------------------------------------------------------
// Fused RMSNorm (over full 2048 row) + RoPE + head-major relayout.
// in: (B*L, ldin) bf16 (first 2048 cols used). out: (B,H,L,128) bf16 * scale.
// ---------------------------------------------------------------------------
__global__ __launch_bounds__(256) void rmsrope_kernel(const unsigned short* __restrict__ in,
                                                      const float* __restrict__ w,
                                                      const float* __restrict__ cs,
                                                      const float* __restrict__ sn,
                                                      unsigned short* __restrict__ out,
                                                      int L, int ldin, float scale) {
  const int row = blockIdx.x;              // B*L
  const int t = threadIdx.x;
  __shared__ __align__(16) unsigned short srow[2048];
  __shared__ float red[4];
  const unsigned short* ir = in + (size_t)row * ldin;
  ushort8 v = *(const ushort8*)(ir + t * 8);
  float vals[8];
  float ss = 0.f;
#pragma unroll
  for (int j = 0; j < 8; ++j) { vals[j] = bf2f(v[j]); ss += vals[j] * vals[j]; }
  *(ushort8*)(srow + t * 8) = v;
#pragma unroll
  for (int m = 1; m < 64; m <<= 1) ss += __shfl_xor(ss, m);
  const int wave = t >> 6, lane = t & 63;
  if (lane == 0) red[wave] = ss;
  __syncthreads();
  const float tot = red[0] + red[1] + red[2] + red[3];
  const float rms = rsqrtf(tot * (1.0f / 2048.0f) + 1e-6f);

  const int n0 = t * 8;
  const int d0 = n0 & 127;
  const int hh = n0 >> 7;
  const float sign = (d0 < 64) ? -1.0f : 1.0f;
  const float* cb = cs + (size_t)row * 128 + d0;
  const float* sb = sn + (size_t)row * 128 + d0;
  ushort8 po = *(const ushort8*)(srow + (n0 ^ 64));
  ushort8 ou;
#pragma unroll
  for (int j = 0; j < 8; ++j) {
    const float self = vals[j] * rms * w[n0 + j];
    const float part = bf2f(po[j]) * rms * w[(n0 ^ 64) + j];
    ou[j] = f2bf((self * cb[j] + sign * part * sb[j]) * scale);
  }
  const int b = row / L, l = row - (row / L) * L;
  *(ushort8*)(out + (((size_t)(b * 16 + hh)) * L + l) * 128 + d0) = ou;
}

// ---------------------------------------------------------------------------
// V transpose: vpre (B, LKV, ldv) bf16 (128 cols per head) -> vt (B,H,128,LKV).
// ---------------------------------------------------------------------------
__global__ __launch_bounds__(256) void vtrans_kernel(const unsigned short* __restrict__ vpre,
                                                     unsigned short* __restrict__ vt,
                                                     int ldv) {
  const int bid = blockIdx.x;              // 32 bh * 16 kv tiles = 512
  const int kt = bid & 15, bh = bid >> 4;
  const int h = bh & 15, b = bh >> 4;
  __shared__ unsigned short lt[64][130];
  const int t = threadIdx.x;
  const int i0 = t >> 4, c0 = (t & 15) * 8;
  const unsigned short* src = vpre + ((size_t)(b * 1024 + kt * 64)) * ldv + h * 128;
#pragma unroll
  for (int ii = 0; ii < 4; ++ii) {
    const int i = i0 + ii * 16;
    ushort8 v = *(const ushort8*)(src + (size_t)i * ldv + c0);
#pragma unroll
    for (int j = 0; j < 8; ++j) lt[i][c0 + j] = v[j];
  }
  __syncthreads();
  const int d0 = t >> 3, j0 = (t & 7) * 8;
  unsigned short* dst = vt + (size_t)bh * 128 * 1024 + kt * 64;
#pragma unroll
  for (int dd = 0; dd < 4; ++dd) {
    const int d = d0 + dd * 32;
    ushort8 o;
#pragma unroll
    for (int jj = 0; jj < 8; ++jj) o[jj] = lt[j0 + jj][d];
    *(ushort8*)(dst + (size_t)d * 1024 + j0) = o;
  }
}

// ---------------------------------------------------------------------------
// Flash cross-attention (R10, proven): KVBLK=128 (2x2 subtiles, R8 layouts),
// QK of BOTH subtiles first, then 4 softmax+PV groups; denominator via VALU
// adds + single shfl_xor(32) + epilogue shfl(crow).
// ---------------------------------------------------------------------------
__global__ __launch_bounds__(512, 2) void attn_kernel(const unsigned short* __restrict__ q,
                                                      const unsigned short* __restrict__ k,
                                                      const unsigned short* __restrict__ vt,
                                                      unsigned short* __restrict__ ao) {
  __shared__ __align__(16) char sK[2][2][64 * 256];  // [buf][sub][kv 64][128 d]
  __shared__ __align__(16) char sV[2][2][64 * 256];  // [buf][sub] paired-d

  // XCD-grouped swizzle: all 16 q-tiles of one bh land on one XCD.
  const int bid0 = blockIdx.x;                      // 512 = 32 bh * 16 qtiles
  const int bid = (bid0 & 7) * 64 + (bid0 >> 3);
  const int qt = bid & 15, bh = bid >> 4;
  const int tid = threadIdx.x;
  const int wave = tid >> 6, lane = tid & 63;
  const int l31 = lane & 31, hi = lane >> 5;
  const bool hib = (hi != 0);

  const unsigned short* qbase = q + (((size_t)bh * 4096) + qt * 256 + wave * 32) * 128;
  const char* kbase = (const char*)(k + (size_t)bh * 1024 * 128);
  const char* vbase = (const char*)(vt + (size_t)bh * 128 * 1024);

  // Q as B-operand frags (32x32x16): col=q=l31, k(d) = step*16 + hi*8 + j
  short8 qb[8];
#pragma unroll
  for (int step = 0; step < 8; ++step)
    qb[step] = *(const short8*)(qbase + (size_t)l31 * 128 + step * 16 + hi * 8);

  f32x16 o[4] = {};        // o[dt]: O[q=crow(r,hi)][d=dt*32+l31]
  float lsum = 0.f;        // partial denominator for q = l31 (this half's rows)

// stage one 128-kv tile (2 subtiles of 64 kv) into buffer BUF
#define STAGE_KV(BUF, KV0) do {                                              \
    _Pragma("unroll")                                                        \
    for (int sub = 0; sub < 2; ++sub) {                                      \
      _Pragma("unroll")                                                      \
      for (int i = 0; i < 2; ++i) {                                          \
        const int p = (i * 512 + tid) * 16;                                  \
        const int row = p >> 8;                                              \
        const int si = (p & 255) ^ ((row & 15) << 4);                        \
        gload_lds16(kbase + (size_t)((KV0) + sub * 64 + row) * 256 + si,     \
                    sK[BUF][sub] + p);                                       \
      }                                                                      \
      _Pragma("unroll")                                                      \
      for (int i = 0; i < 2; ++i) {                                          \
        const int p = (i * 512 + tid) * 16;                                  \
        const int row = p >> 8;                                              \
        const int si = (p & 255) ^ ((row & 15) << 4);                        \
        const int d = 2 * row + (si >> 7);                                   \
        gload_lds16(vbase + (size_t)d * 2048 + ((KV0) + sub * 64) * 2 +      \
                    (si & 127), sV[BUF][sub] + p);                           \
      }                                                                      \
    }                                                                        \
  } while (0)

// QK for one 64-kv subtile: accumulate scores into S0 (kv 0..31), S1 (32..63)
#define QK(K, S0, S1) do {                                                   \
    const int ksw = (l31 & 15) << 4;                                         \
    _Pragma("unroll") for (int step = 0; step < 8; ++step) {                 \
      const int cb2 = step * 32 + hi * 16;                                   \
      short8 kf0 = *(const short8*)((K) + l31 * 256 + (cb2 ^ ksw));          \
      short8 kf1 = *(const short8*)((K) + (32 + l31) * 256 + (cb2 ^ ksw));   \
      S0 = __builtin_amdgcn_mfma_f32_32x32x16_bf16(kf0, qb[step], S0, 0,0,0);\
      S1 = __builtin_amdgcn_mfma_f32_32x32x16_bf16(kf1, qb[step], S1, 0,0,0);\
    }                                                                        \
  } while (0)

// softmax + PV for one 32-kv block F (within a 64-kv subtile) from scores SS
#define SOFTMAX_PV(V, SS, F) do {                                            \
    float p_[16];                                                            \
    _Pragma("unroll") for (int r = 0; r < 16; ++r) p_[r] = exp2f((SS)[r]);   \
    lsum += (((p_[0]+p_[1])+(p_[2]+p_[3])) + ((p_[4]+p_[5])+(p_[6]+p_[7])))  \
          + (((p_[8]+p_[9])+(p_[10]+p_[11])) + ((p_[12]+p_[13])+(p_[14]+p_[15])));\
    const unsigned w0 = cvtpk_bf16(p_[0], p_[1]),  w1 = cvtpk_bf16(p_[2], p_[3]), \
                   w2 = cvtpk_bf16(p_[4], p_[5]),  w3 = cvtpk_bf16(p_[6], p_[7]), \
                   w4 = cvtpk_bf16(p_[8], p_[9]),  w5 = cvtpk_bf16(p_[10], p_[11]),\
                   w6 = cvtpk_bf16(p_[12], p_[13]),w7 = cvtpk_bf16(p_[14], p_[15]);\
    const unsigned x0 = (unsigned)__shfl_xor((int)(hib ? w0 : w2), 32);      \
    const unsigned x1 = (unsigned)__shfl_xor((int)(hib ? w1 : w3), 32);      \
    const unsigned x2 = (unsigned)__shfl_xor((int)(hib ? w4 : w6), 32);      \
    const unsigned x3 = (unsigned)__shfl_xor((int)(hib ? w5 : w7), 32);      \
    const short8 fr0 = mk8(hib ? x0 : w0, hib ? x1 : w1,                     \
                           hib ? w2 : x0, hib ? w3 : x1);                    \
    const short8 fr1 = mk8(hib ? x2 : w4, hib ? x3 : w5,                     \
                           hib ? w6 : x2, hib ? w7 : x3);                    \
    _Pragma("unroll") for (int kstep = 0; kstep < 2; ++kstep) {              \
      const short8 pa = kstep ? fr1 : fr0;                                   \
      const int colb = (F) * 64 + kstep * 32 + hi * 16;                      \
      _Pragma("unroll") for (int dt = 0; dt < 4; ++dt) {                     \
        const int vrow = dt * 16 + (l31 >> 1);                               \
        const int inner = (l31 & 1) * 128 + colb;                            \
        short8 vf = *(const short8*)((V) + vrow * 256 +                      \
                                     (inner ^ ((vrow & 15) << 4)));          \
        o[dt] = __builtin_amdgcn_mfma_f32_32x32x16_bf16(pa, vf, o[dt], 0,0,0);\
      }                                                                      \
    }                                                                        \
  } while (0)

// full 128-kv tile: QK both subtiles first, then the 4 softmax+PV groups
#define TILE(BUF) do {                                                       \
    f32x16 s0 = {}, s1 = {}, s2 = {}, s3 = {};                               \
    QK(sK[BUF][0], s0, s1);                                                  \
    QK(sK[BUF][1], s2, s3);                                                  \
    SOFTMAX_PV(sV[BUF][0], s0, 0);                                           \
    SOFTMAX_PV(sV[BUF][0], s1, 1);                                           \
    SOFTMAX_PV(sV[BUF][1], s2, 0);                                           \
    SOFTMAX_PV(sV[BUF][1], s3, 1);                                           \
  } while (0)

  STAGE_KV(0, 0);
  __syncthreads();

#pragma unroll 1
  for (int kt2 = 0; kt2 < 4; ++kt2) {
    STAGE_KV(1, (2 * kt2 + 1) * 128);    // prefetch odd 128-tile into buf1
    TILE(0);
    __syncthreads();
    if (kt2 < 3) STAGE_KV(0, (2 * kt2 + 2) * 128);  // prefetch even 128-tile
    TILE(1);
    __syncthreads();
  }
#undef STAGE_KV
#undef QK
#undef SOFTMAX_PV
#undef TILE

  // ---- epilogue: denom(q=l31) = own half + partner half; redistribute ----
  lsum += __shfl_xor(lsum, 32);
  const float linv = 1.0f / lsum;
  const int b = bh >> 4, h = bh & 15;
#pragma unroll
  for (int r = 0; r < 16; ++r) {
    const int crow = (r & 3) + 8 * (r >> 2) + 4 * hi;
    const float inv = __shfl(linv, crow);    // lane crow holds denom(q=crow)
    const int qg = qt * 256 + wave * 32 + crow;
    const size_t orow = ((size_t)b * 4096 + qg) * 2048 + h * 128;
#pragma unroll
    for (int dt = 0; dt < 4; ++dt)
      ao[orow + dt * 32 + l31] = f2bf(o[dt][r] * inv);
  }
}

// ---------------------------------------------------------------------------
extern "C" void kernel_launch(void* const* d_in, const int* in_sizes, int n_in,
                              void* d_out, int out_size, void* d_ws, size_t ws_size,
                              hipStream_t stream) {
  (void)in_sizes; (void)n_in; (void)out_size; (void)ws_size;
  const float* x      = (const float*)d_in[0];
  const float* y      = (const float*)d_in[1];
  const float* x_cos  = (const float*)d_in[2];
  const float* x_sin  = (const float*)d_in[3];
  const float* y_cos  = (const float*)d_in[4];
  const float* y_sin  = (const float*)d_in[5];
  const float* Wq     = (const float*)d_in[6];
  const float* bq     = (const float*)d_in[7];
  const float* Wk     = (const float*)d_in[8];
  const float* bk     = (const float*)d_in[9];
  const float* Wv     = (const float*)d_in[10];
  const float* bv     = (const float*)d_in[11];
  const float* Wo     = (const float*)d_in[12];
  const float* bo     = (const float*)d_in[13];
  const float* rmsq_w = (const float*)d_in[14];
  const float* rmsk_w = (const float*)d_in[15];
  const float* ln_w   = (const float*)d_in[16];
  const float* ln_b   = (const float*)d_in[17];

  char* ws = (char*)d_ws;
  unsigned short* xb    = (unsigned short*)(ws + 0);           // 33,554,432
  unsigned short* Wqb   = (unsigned short*)(ws + 33554432);    //  8,388,608
  unsigned short* Wkb   = (unsigned short*)(ws + 41943040);    //  4,194,304 (contiguous with Wvb)
  unsigned short* Wvb   = (unsigned short*)(ws + 46137344);    //  4,194,304
  unsigned short* Wob   = (unsigned short*)(ws + 50331648);    //  8,388,608
  unsigned short* ynb   = (unsigned short*)(ws + 58720256);    //  4,194,304
  unsigned short* kvpre = (unsigned short*)(ws + 62914560);    // 16,777,216 (2048 x 4096, aliased by qpre later)
  unsigned short* qpre  = (unsigned short*)(ws + 62914560);    // 33,554,432
  unsigned short* qr    = (unsigned short*)(ws + 96468992);    // 33,554,432
  unsigned short* kr    = (unsigned short*)(ws + 130023424);   //  8,388,608
  unsigned short* vt    = (unsigned short*)(ws + 138412032);   //  8,388,608
  unsigned short* ao    = xb;

  const float qscale = 1.4426950408889634f * 0.08838834764831843f; // log2e/sqrt(128)

  cvt_kernel<<<2048, 256, 0, stream>>>(x, xb, (2 * 4096 * 2048) / 4);
  cvt4_kernel<<<2048, 256, 0, stream>>>(Wq, Wk, Wv, Wo, Wqb, Wkb, Wvb, Wob,
                                        (2048 * 2048) / 4, (2048 * 1024) / 4,
                                        (2048 * 1024) / 4, (2048 * 2048) / 4);
  ln_kernel<<<2048, 256, 0, stream>>>(y, ln_w, ln_b, ynb);

  // merged K+V projection on the fast path: C[2048,4096] = yn @ [Wk;Wv]^T
  gemm256<0><<<128, 512, 0, stream>>>(ynb, Wkb, bk, bv, 2048, kvpre, 2048, 4096, 1024);
  rmsrope_kernel<<<2048, 256, 0, stream>>>(kvpre, rmsk_w, y_cos, y_sin, kr, 1024, 4096, 1.0f);
  vtrans_kernel<<<512, 256, 0, stream>>>(kvpre + 2048, vt, 4096);

  gemm256<0><<<256, 512, 0, stream>>>(xb, Wqb, bq, bq, 2048, qpre, 8192, 2048, 2048);
  rmsrope_kernel<<<8192, 256, 0, stream>>>(qpre, rmsq_w, x_cos, x_sin, qr, 4096, 2048, qscale);

  attn_kernel<<<512, 512, 0, stream>>>(qr, kr, vt, ao);

  gemm256<1><<<256, 512, 0, stream>>>(ao, Wob, bo, bo, 2048, (float*)d_out, 8192, 2048, 2048);
}

// Round 13
// 303.423 us; speedup vs baseline: 1.3316x; 1.0319x over previous
//
#include <hip/hip_runtime.h>

// ---------------------------------------------------------------------------
// ConditionalCrossAttentionBlock: LN -> K/V proj -> RMS(Q proj) -> RoPE ->
// 16-head cross attention (LQ=4096, LKV=1024, Dh=128) -> O proj.
// R13: launch fusion — 5 launches: prep(ln+cvt5), gemm_dual(Q+KV), post
// (rmsrope_q + rmsrope_k + vtrans), attn (R10 proven), O gemm. Kernel bodies
// unchanged; ws relayout so Q/KV outputs are disjoint (kr/vt reuse dead
// weight regions). KV blocks backfill CUs behind Q blocks.
// ---------------------------------------------------------------------------

typedef __attribute__((ext_vector_type(8))) short    short8;
typedef __attribute__((ext_vector_type(8))) unsigned short ushort8;
typedef __attribute__((ext_vector_type(4))) unsigned short ushort4v;
typedef __attribute__((ext_vector_type(4))) float    f32x4;
typedef __attribute__((ext_vector_type(16))) float   f32x16;
typedef __attribute__((ext_vector_type(4))) unsigned int uint4v;

#define DEV __device__ __forceinline__

DEV unsigned short f2bf(float f) {
  unsigned int u = __builtin_bit_cast(unsigned int, f);
  u += 0x7FFFu + ((u >> 16) & 1u);        // RNE, inputs are finite
  return (unsigned short)(u >> 16);
}
DEV float bf2f(unsigned short h) {
  return __builtin_bit_cast(float, ((unsigned int)h) << 16);
}
DEV unsigned int cvtpk_bf16(float lo, float hi) {
  unsigned int r;
  asm("v_cvt_pk_bf16_f32 %0, %1, %2" : "=v"(r) : "v"(lo), "v"(hi));
  return r;
}
DEV short8 mk8(unsigned a, unsigned b, unsigned c, unsigned d) {
  uint4v t; t.x = a; t.y = b; t.z = c; t.w = d;
  return __builtin_bit_cast(short8, t);
}

DEV void gload_lds16(const void* g, void* l) {
  __builtin_amdgcn_global_load_lds(
      (const __attribute__((address_space(1))) void*)g,
      (__attribute__((address_space(3))) void*)l, 16, 0, 0);
}

// ---------------------------------------------------------------------------
// prep: blocks [0,2048) = LayerNorm rows; [2048,3584) = grid-stride f32->bf16
// over {x, Wq, Wk, Wv, Wo}.
// ---------------------------------------------------------------------------
__global__ __launch_bounds__(256) void prep_kernel(const float* __restrict__ y,
                                                   const float* __restrict__ lnw,
                                                   const float* __restrict__ lnb,
                                                   unsigned short* __restrict__ yn,
                                                   const float* __restrict__ x,
                                                   const float* __restrict__ Wq,
                                                   const float* __restrict__ Wk,
                                                   const float* __restrict__ Wv,
                                                   const float* __restrict__ Wo,
                                                   unsigned short* __restrict__ xb,
                                                   unsigned short* __restrict__ Wqb,
                                                   unsigned short* __restrict__ Wkb,
                                                   unsigned short* __restrict__ Wvb,
                                                   unsigned short* __restrict__ Wob) {
  const int t = threadIdx.x;
  if (blockIdx.x < 2048) {
    // ---- LayerNorm over one row of 1024 ----
    const int row = blockIdx.x;
    const float* yr = y + (size_t)row * 1024;
    float4 v = *(const float4*)(yr + t * 4);
    float s1 = v.x + v.y + v.z + v.w;
    float s2 = v.x * v.x + v.y * v.y + v.z * v.z + v.w * v.w;
#pragma unroll
    for (int m = 1; m < 64; m <<= 1) {
      s1 += __shfl_xor(s1, m);
      s2 += __shfl_xor(s2, m);
    }
    __shared__ float red[8];
    const int wave = t >> 6, lane = t & 63;
    if (lane == 0) { red[wave] = s1; red[4 + wave] = s2; }
    __syncthreads();
    s1 = red[0] + red[1] + red[2] + red[3];
    s2 = red[4] + red[5] + red[6] + red[7];
    const float mu = s1 * (1.0f / 1024.0f);
    const float var = s2 * (1.0f / 1024.0f) - mu * mu;
    const float rs = rsqrtf(var + 1e-6f);
    ushort4v o;
    o.x = f2bf((v.x - mu) * rs * lnw[t * 4 + 0] + lnb[t * 4 + 0]);
    o.y = f2bf((v.y - mu) * rs * lnw[t * 4 + 1] + lnb[t * 4 + 1]);
    o.z = f2bf((v.z - mu) * rs * lnw[t * 4 + 2] + lnb[t * 4 + 2]);
    o.w = f2bf((v.w - mu) * rs * lnw[t * 4 + 3] + lnb[t * 4 + 3]);
    *(ushort4v*)(yn + (size_t)row * 1024 + t * 4) = o;
    return;
  }
  // ---- 5-segment convert (float4 units) ----
  const int nx = 4194304, nwq = 1048576, nwk = 524288, nwv = 524288;
  const int total = 7340032;
  int i = (blockIdx.x - 2048) * 256 + t;
  const int stride = 1536 * 256;
  for (; i < total; i += stride) {
    int j = i;
    const float* s; unsigned short* d;
    if (j < nx) { s = x; d = xb; }
    else if ((j -= nx) < nwq) { s = Wq; d = Wqb; }
    else if ((j -= nwq) < nwk) { s = Wk; d = Wkb; }
    else if ((j -= nwk) < nwv) { s = Wv; d = Wvb; }
    else { j -= nwv; s = Wo; d = Wob; }
    float4 v = *(const float4*)(s + (size_t)j * 4);
    ushort4v o;
    o.x = f2bf(v.x); o.y = f2bf(v.y); o.z = f2bf(v.z); o.w = f2bf(v.w);
    *(ushort4v*)(d + (size_t)j * 4) = o;
  }
}

// ---------------------------------------------------------------------------
// 256x256 8-phase pipelined GEMM body (T2+T3+T4+T5).
// C = A[M,K] @ W[N,K]^T + bias; bias = n<nsplit ? bias0[n] : bias1[n-nsplit].
// ---------------------------------------------------------------------------
template <int EPI>
DEV void gemm256_body(const unsigned short* __restrict__ A,
                      const unsigned short* __restrict__ W,
                      const float* __restrict__ bias0,
                      const float* __restrict__ bias1,
                      int nsplit, void* __restrict__ Cout,
                      int M, int N, int K,
                      int bidLocal, int nwg, char* ldsb, int tid) {
  const int wave = tid >> 6, lane = tid & 63;
  const int lg = lane >> 4, l15 = lane & 15;
  const int wm = wave >> 2, wn = wave & 3;

  const int wgid = (bidLocal & 7) * (nwg >> 3) + (bidLocal >> 3);
  const int nbn = N >> 8;
  const int m0 = (wgid / nbn) * 256;
  const int n0 = (wgid % nbn) * 256;

  const char* Ab = (const char*)A;
  const char* Wb = (const char*)W;
  const size_t ld = (size_t)K * 2;
  const int NT = K >> 6;
  const int NI = NT >> 1;

  const int prow = tid >> 3;
  const int psw  = ((tid * 16) & 127) ^ ((prow & 7) << 4);
  const int pdst = tid * 16;
  const char* pAg = Ab + (size_t)(m0 + prow) * ld + psw;
  const char* pBg = Wb + (size_t)(n0 + prow) * ld + psw;

  f32x4 acc[8][4] = {};
  short8 af[4][2];
  short8 bf[4][2];

#define LDSB(BUF, SEG) (ldsb + ((BUF) * 4 + (SEG)) * 16384)

#define STG(BUF, HALF, ISB, TAU) do {                                         \
    const char* _g = ((ISB) ? pBg : pAg) + (size_t)(HALF) * 128 * ld +        \
                     (size_t)(TAU) * 128;                                     \
    char* _l = LDSB(BUF, (ISB) * 2 + (HALF));                                 \
    gload_lds16(_g, _l + pdst);                                               \
    gload_lds16(_g + 64 * ld, _l + pdst + 8192);                              \
  } while (0)

#define LDA(BUF, H) do {                                                      \
    const char* _b = LDSB(BUF, wm);                                           \
    _Pragma("unroll") for (int mfl = 0; mfl < 4; ++mfl) {                     \
      const int _r = (H) * 64 + mfl * 16 + l15;                               \
      _Pragma("unroll") for (int ks = 0; ks < 2; ++ks)                        \
        af[mfl][ks] = *(const short8*)(_b + _r * 128 +                        \
                        ((ks * 64 + lg * 16) ^ ((_r & 7) << 4)));             \
    }                                                                         \
  } while (0)

#define LDB(BUF, G) do {                                                      \
    const char* _b = LDSB(BUF, 2 + (wn >> 1));                                \
    _Pragma("unroll") for (int nfl = 0; nfl < 2; ++nfl) {                     \
      const int _r = (wn & 1) * 64 + (G) * 32 + nfl * 16 + l15;               \
      _Pragma("unroll") for (int ks = 0; ks < 2; ++ks)                        \
        bf[(G) * 2 + nfl][ks] = *(const short8*)(_b + _r * 128 +              \
                        ((ks * 64 + lg * 16) ^ ((_r & 7) << 4)));             \
    }                                                                         \
  } while (0)

#define MFMA_Q(H, G) do {                                                     \
    __builtin_amdgcn_s_setprio(1);                                            \
    _Pragma("unroll") for (int ks = 0; ks < 2; ++ks)                          \
    _Pragma("unroll") for (int mfl = 0; mfl < 4; ++mfl)                       \
    _Pragma("unroll") for (int nfl = 0; nfl < 2; ++nfl)                       \
      acc[(H) * 4 + mfl][(G) * 2 + nfl] =                                     \
        __builtin_amdgcn_mfma_f32_16x16x32_bf16(af[mfl][ks],                  \
            bf[(G) * 2 + nfl][ks], acc[(H) * 4 + mfl][(G) * 2 + nfl], 0,0,0); \
    __builtin_amdgcn_s_setprio(0);                                            \
  } while (0)

#define BAR() __builtin_amdgcn_s_barrier()
#define LGKM0() do { asm volatile("s_waitcnt lgkmcnt(0)" ::: "memory");       \
    __builtin_amdgcn_sched_barrier(0); } while (0)
#define VM4() asm volatile("s_waitcnt vmcnt(4)" ::: "memory")
#define VM0() asm volatile("s_waitcnt vmcnt(0)" ::: "memory")

  STG(0, 0, 0, 0); STG(0, 1, 0, 0); STG(0, 0, 1, 0); STG(0, 1, 1, 0);
  STG(1, 0, 1, 1); STG(1, 1, 1, 1);
  VM4(); BAR();

  for (int t = 0; t < NI - 1; ++t) {
    const int t2 = 2 * t;
    LDA(0, 0); LDB(0, 0); STG(1, 0, 0, t2 + 1);
    BAR(); LGKM0(); MFMA_Q(0, 0); BAR();
    LDB(0, 1); STG(1, 1, 0, t2 + 1);
    BAR(); LGKM0(); MFMA_Q(0, 1); BAR();
    LDA(0, 1); STG(0, 0, 1, t2 + 2);
    BAR(); LGKM0(); MFMA_Q(1, 1); BAR();
    STG(0, 1, 1, t2 + 2);
    BAR(); MFMA_Q(1, 0); VM4(); BAR();
    LDA(1, 0); LDB(1, 0); STG(0, 0, 0, t2 + 2);
    BAR(); LGKM0(); MFMA_Q(0, 0); BAR();
    LDB(1, 1); STG(0, 1, 0, t2 + 2);
    BAR(); LGKM0(); MFMA_Q(0, 1); BAR();
    LDA(1, 1); STG(1, 0, 1, t2 + 3);
    BAR(); LGKM0(); MFMA_Q(1, 1); BAR();
    STG(1, 1, 1, t2 + 3);
    BAR(); MFMA_Q(1, 0); VM4(); BAR();
  }

  LDA(0, 0); LDB(0, 0); STG(1, 0, 0, NT - 1);
  BAR(); LGKM0(); MFMA_Q(0, 0); BAR();
  LDB(0, 1); STG(1, 1, 0, NT - 1);
  BAR(); LGKM0(); MFMA_Q(0, 1); BAR();
  LDA(0, 1);
  BAR(); LGKM0(); MFMA_Q(1, 1); BAR();
  BAR(); MFMA_Q(1, 0); VM0(); BAR();
  LDA(1, 0); LDB(1, 0); LGKM0(); MFMA_Q(0, 0);
  LDB(1, 1); LGKM0(); MFMA_Q(0, 1);
  LDA(1, 1); LGKM0(); MFMA_Q(1, 1);
  MFMA_Q(1, 0);

#undef STG
#undef LDA
#undef LDB
#undef MFMA_Q
#undef BAR
#undef LGKM0
#undef VM4
#undef VM0
#undef LDSB

#pragma unroll
  for (int nf = 0; nf < 4; ++nf) {
    const int n = n0 + wn * 64 + nf * 16 + l15;
    const float bv = (n < nsplit) ? bias0[n] : bias1[n - nsplit];
#pragma unroll
    for (int mf = 0; mf < 8; ++mf) {
      const int mB = m0 + wm * 128 + mf * 16 + lg * 4;
#pragma unroll
      for (int r = 0; r < 4; ++r) {
        const float v = acc[mf][nf][r] + bv;
        if constexpr (EPI == 0)
          ((unsigned short*)Cout)[(size_t)(mB + r) * N + n] = f2bf(v);
        else
          ((float*)Cout)[(size_t)(mB + r) * N + n] = v;
      }
    }
  }
}

// Q GEMM (blocks 0..255) + KV GEMM (blocks 256..383) in one launch.
__global__ __launch_bounds__(512, 2) void gemm_dual(const unsigned short* __restrict__ xb,
                                                    const unsigned short* __restrict__ Wqb,
                                                    const float* __restrict__ bq,
                                                    unsigned short* __restrict__ qpre,
                                                    const unsigned short* __restrict__ ynb,
                                                    const unsigned short* __restrict__ Wkb,
                                                    const float* __restrict__ bk,
                                                    const float* __restrict__ bv,
                                                    unsigned short* __restrict__ kvpre) {
  __shared__ __align__(16) char lds[2][4][16384];
  if (blockIdx.x < 256)
    gemm256_body<0>(xb, Wqb, bq, bq, 2048, qpre, 8192, 2048, 2048,
                    blockIdx.x, 256, &lds[0][0][0], threadIdx.x);
  else
    gemm256_body<0>(ynb, Wkb, bk, bv, 2048, kvpre, 2048, 4096, 1024,
                    blockIdx.x - 256, 128, &lds[0][0][0], threadIdx.x);
}

// O projection (f32 out).
__global__ __launch_bounds__(512, 2) void gemm_f32(const unsigned short* __restrict__ A,
                                                   const unsigned short* __restrict__ W,
                                                   const float* __restrict__ bias,
                                                   float* __restrict__ C,
                                                   int M, int N, int K) {
  __shared__ __align__(16) char lds[2][4][16384];
  gemm256_body<1>(A, W, bias, bias, N, C, M, N, K,
                  blockIdx.x, 256, &lds[0][0][0], threadIdx.x);
}

// ---------------------------------------------------------------------------
// post: blocks [0,8192) rmsrope_q; [8192,10240) rmsrope_k; [10240,10752)
// vtrans. All depend only on gemm_dual; disjoint buffers.
// ---------------------------------------------------------------------------
DEV void rmsrope_body(const unsigned short* __restrict__ in,
                      const float* __restrict__ w,
                      const float* __restrict__ cs,
                      const float* __restrict__ sn,
                      unsigned short* __restrict__ out,
                      int L, int ldin, float scale, int row,
                      unsigned short* srow, float* red) {
  const int t = threadIdx.x;
  const unsigned short* ir = in + (size_t)row * ldin;
  ushort8 v = *(const ushort8*)(ir + t * 8);
  float vals[8];
  float ss = 0.f;
#pragma unroll
  for (int j = 0; j < 8; ++j) { vals[j] = bf2f(v[j]); ss += vals[j] * vals[j]; }
  *(ushort8*)(srow + t * 8) = v;
#pragma unroll
  for (int m = 1; m < 64; m <<= 1) ss += __shfl_xor(ss, m);
  const int wave = t >> 6, lane = t & 63;
  if (lane == 0) red[wave] = ss;
  __syncthreads();
  const float tot = red[0] + red[1] + red[2] + red[3];
  const float rms = rsqrtf(tot * (1.0f / 2048.0f) + 1e-6f);

  const int n0 = t * 8;
  const int d0 = n0 & 127;
  const int hh = n0 >> 7;
  const float sign = (d0 < 64) ? -1.0f : 1.0f;
  const float* cb = cs + (size_t)row * 128 + d0;
  const float* sb = sn + (size_t)row * 128 + d0;
  ushort8 po = *(const ushort8*)(srow + (n0 ^ 64));
  ushort8 ou;
#pragma unroll
  for (int j = 0; j < 8; ++j) {
    const float self = vals[j] * rms * w[n0 + j];
    const float part = bf2f(po[j]) * rms * w[(n0 ^ 64) + j];
    ou[j] = f2bf((self * cb[j] + sign * part * sb[j]) * scale);
  }
  const int b = row / L, l = row - (row / L) * L;
  *(ushort8*)(out + (((size_t)(b * 16 + hh)) * L + l) * 128 + d0) = ou;
}

DEV void vtrans_body(const unsigned short* __restrict__ vpre,
                     unsigned short* __restrict__ vt, int ldv, int bid,
                     unsigned short (*lt)[130]) {
  const int kt = bid & 15, bh = bid >> 4;
  const int h = bh & 15, b = bh >> 4;
  const int t = threadIdx.x;
  const int i0 = t >> 4, c0 = (t & 15) * 8;
  const unsigned short* src = vpre + ((size_t)(b * 1024 + kt * 64)) * ldv + h * 128;
#pragma unroll
  for (int ii = 0; ii < 4; ++ii) {
    const int i = i0 + ii * 16;
    ushort8 v = *(const ushort8*)(src + (size_t)i * ldv + c0);
#pragma unroll
    for (int j = 0; j < 8; ++j) lt[i][c0 + j] = v[j];
  }
  __syncthreads();
  const int d0 = t >> 3, j0 = (t & 7) * 8;
  unsigned short* dst = vt + (size_t)bh * 128 * 1024 + kt * 64;
#pragma unroll
  for (int dd = 0; dd < 4; ++dd) {
    const int d = d0 + dd * 32;
    ushort8 o;
#pragma unroll
    for (int jj = 0; jj < 8; ++jj) o[jj] = lt[j0 + jj][d];
    *(ushort8*)(dst + (size_t)d * 1024 + j0) = o;
  }
}

__global__ __launch_bounds__(256) void post_kernel(const unsigned short* __restrict__ qpre,
                                                   const float* __restrict__ rmsq_w,
                                                   const float* __restrict__ x_cos,
                                                   const float* __restrict__ x_sin,
                                                   unsigned short* __restrict__ qr,
                                                   const unsigned short* __restrict__ kvpre,
                                                   const float* __restrict__ rmsk_w,
                                                   const float* __restrict__ y_cos,
                                                   const float* __restrict__ y_sin,
                                                   unsigned short* __restrict__ kr,
                                                   unsigned short* __restrict__ vt,
                                                   float qscale) {
  __shared__ __align__(16) unsigned short srow[2048];
  __shared__ float red[4];
  __shared__ unsigned short lt[64][130];
  const int b = blockIdx.x;
  if (b < 8192) {
    rmsrope_body(qpre, rmsq_w, x_cos, x_sin, qr, 4096, 2048, qscale, b, srow, red);
  } else if (b < 10240) {
    rmsrope_body(kvpre, rmsk_w, y_cos, y_sin, kr, 1024, 4096, 1.0f, b - 8192, srow, red);
  } else {
    vtrans_body(kvpre + 2048, vt, 4096, b - 10240, lt);
  }
}

// ---------------------------------------------------------------------------
// Flash cross-attention (R10, proven): KVBLK=128 (2x2 subtiles, R8 layouts),
// QK of BOTH subtiles first, then 4 softmax+PV groups; denominator via VALU
// adds + single shfl_xor(32) + epilogue shfl(crow).
// ---------------------------------------------------------------------------
__global__ __launch_bounds__(512, 2) void attn_kernel(const unsigned short* __restrict__ q,
                                                      const unsigned short* __restrict__ k,
                                                      const unsigned short* __restrict__ vt,
                                                      unsigned short* __restrict__ ao) {
  __shared__ __align__(16) char sK[2][2][64 * 256];  // [buf][sub][kv 64][128 d]
  __shared__ __align__(16) char sV[2][2][64 * 256];  // [buf][sub] paired-d

  const int bid0 = blockIdx.x;                      // 512 = 32 bh * 16 qtiles
  const int bid = (bid0 & 7) * 64 + (bid0 >> 3);
  const int qt = bid & 15, bh = bid >> 4;
  const int tid = threadIdx.x;
  const int wave = tid >> 6, lane = tid & 63;
  const int l31 = lane & 31, hi = lane >> 5;
  const bool hib = (hi != 0);

  const unsigned short* qbase = q + (((size_t)bh * 4096) + qt * 256 + wave * 32) * 128;
  const char* kbase = (const char*)(k + (size_t)bh * 1024 * 128);
  const char* vbase = (const char*)(vt + (size_t)bh * 128 * 1024);

  short8 qb[8];
#pragma unroll
  for (int step = 0; step < 8; ++step)
    qb[step] = *(const short8*)(qbase + (size_t)l31 * 128 + step * 16 + hi * 8);

  f32x16 o[4] = {};        // o[dt]: O[q=crow(r,hi)][d=dt*32+l31]
  float lsum = 0.f;

#define STAGE_KV(BUF, KV0) do {                                              \
    _Pragma("unroll")                                                        \
    for (int sub = 0; sub < 2; ++sub) {                                      \
      _Pragma("unroll")                                                      \
      for (int i = 0; i < 2; ++i) {                                          \
        const int p = (i * 512 + tid) * 16;                                  \
        const int row = p >> 8;                                              \
        const int si = (p & 255) ^ ((row & 15) << 4);                        \
        gload_lds16(kbase + (size_t)((KV0) + sub * 64 + row) * 256 + si,     \
                    sK[BUF][sub] + p);                                       \
      }                                                                      \
      _Pragma("unroll")                                                      \
      for (int i = 0; i < 2; ++i) {                                          \
        const int p = (i * 512 + tid) * 16;                                  \
        const int row = p >> 8;                                              \
        const int si = (p & 255) ^ ((row & 15) << 4);                        \
        const int d = 2 * row + (si >> 7);                                   \
        gload_lds16(vbase + (size_t)d * 2048 + ((KV0) + sub * 64) * 2 +      \
                    (si & 127), sV[BUF][sub] + p);                           \
      }                                                                      \
    }                                                                        \
  } while (0)

#define QK(K, S0, S1) do {                                                   \
    const int ksw = (l31 & 15) << 4;                                         \
    _Pragma("unroll") for (int step = 0; step < 8; ++step) {                 \
      const int cb2 = step * 32 + hi * 16;                                   \
      short8 kf0 = *(const short8*)((K) + l31 * 256 + (cb2 ^ ksw));          \
      short8 kf1 = *(const short8*)((K) + (32 + l31) * 256 + (cb2 ^ ksw));   \
      S0 = __builtin_amdgcn_mfma_f32_32x32x16_bf16(kf0, qb[step], S0, 0,0,0);\
      S1 = __builtin_amdgcn_mfma_f32_32x32x16_bf16(kf1, qb[step], S1, 0,0,0);\
    }                                                                        \
  } while (0)

#define SOFTMAX_PV(V, SS, F) do {                                            \
    float p_[16];                                                            \
    _Pragma("unroll") for (int r = 0; r < 16; ++r) p_[r] = exp2f((SS)[r]);   \
    lsum += (((p_[0]+p_[1])+(p_[2]+p_[3])) + ((p_[4]+p_[5])+(p_[6]+p_[7])))  \
          + (((p_[8]+p_[9])+(p_[10]+p_[11])) + ((p_[12]+p_[13])+(p_[14]+p_[15])));\
    const unsigned w0 = cvtpk_bf16(p_[0], p_[1]),  w1 = cvtpk_bf16(p_[2], p_[3]), \
                   w2 = cvtpk_bf16(p_[4], p_[5]),  w3 = cvtpk_bf16(p_[6], p_[7]), \
                   w4 = cvtpk_bf16(p_[8], p_[9]),  w5 = cvtpk_bf16(p_[10], p_[11]),\
                   w6 = cvtpk_bf16(p_[12], p_[13]),w7 = cvtpk_bf16(p_[14], p_[15]);\
    const unsigned x0 = (unsigned)__shfl_xor((int)(hib ? w0 : w2), 32);      \
    const unsigned x1 = (unsigned)__shfl_xor((int)(hib ? w1 : w3), 32);      \
    const unsigned x2 = (unsigned)__shfl_xor((int)(hib ? w4 : w6), 32);      \
    const unsigned x3 = (unsigned)__shfl_xor((int)(hib ? w5 : w7), 32);      \
    const short8 fr0 = mk8(hib ? x0 : w0, hib ? x1 : w1,                     \
                           hib ? w2 : x0, hib ? w3 : x1);                    \
    const short8 fr1 = mk8(hib ? x2 : w4, hib ? x3 : w5,                     \
                           hib ? w6 : x2, hib ? w7 : x3);                    \
    _Pragma("unroll") for (int kstep = 0; kstep < 2; ++kstep) {              \
      const short8 pa = kstep ? fr1 : fr0;                                   \
      const int colb = (F) * 64 + kstep * 32 + hi * 16;                      \
      _Pragma("unroll") for (int dt = 0; dt < 4; ++dt) {                     \
        const int vrow = dt * 16 + (l31 >> 1);                               \
        const int inner = (l31 & 1) * 128 + colb;                            \
        short8 vf = *(const short8*)((V) + vrow * 256 +                      \
                                     (inner ^ ((vrow & 15) << 4)));          \
        o[dt] = __builtin_amdgcn_mfma_f32_32x32x16_bf16(pa, vf, o[dt], 0,0,0);\
      }                                                                      \
    }                                                                        \
  } while (0)

#define TILE(BUF) do {                                                       \
    f32x16 s0 = {}, s1 = {}, s2 = {}, s3 = {};                               \
    QK(sK[BUF][0], s0, s1);                                                  \
    QK(sK[BUF][1], s2, s3);                                                  \
    SOFTMAX_PV(sV[BUF][0], s0, 0);                                           \
    SOFTMAX_PV(sV[BUF][0], s1, 1);                                           \
    SOFTMAX_PV(sV[BUF][1], s2, 0);                                           \
    SOFTMAX_PV(sV[BUF][1], s3, 1);                                           \
  } while (0)

  STAGE_KV(0, 0);
  __syncthreads();

#pragma unroll 1
  for (int kt2 = 0; kt2 < 4; ++kt2) {
    STAGE_KV(1, (2 * kt2 + 1) * 128);
    TILE(0);
    __syncthreads();
    if (kt2 < 3) STAGE_KV(0, (2 * kt2 + 2) * 128);
    TILE(1);
    __syncthreads();
  }
#undef STAGE_KV
#undef QK
#undef SOFTMAX_PV
#undef TILE

  lsum += __shfl_xor(lsum, 32);
  const float linv = 1.0f / lsum;
  const int b = bh >> 4, h = bh & 15;
#pragma unroll
  for (int r = 0; r < 16; ++r) {
    const int crow = (r & 3) + 8 * (r >> 2) + 4 * hi;
    const float inv = __shfl(linv, crow);
    const int qg = qt * 256 + wave * 32 + crow;
    const size_t orow = ((size_t)b * 4096 + qg) * 2048 + h * 128;
#pragma unroll
    for (int dt = 0; dt < 4; ++dt)
      ao[orow + dt * 32 + l31] = f2bf(o[dt][r] * inv);
  }
}

// ---------------------------------------------------------------------------
extern "C" void kernel_launch(void* const* d_in, const int* in_sizes, int n_in,
                              void* d_out, int out_size, void* d_ws, size_t ws_size,
                              hipStream_t stream) {
  (void)in_sizes; (void)n_in; (void)out_size; (void)ws_size;
  const float* x      = (const float*)d_in[0];
  const float* y      = (const float*)d_in[1];
  const float* x_cos  = (const float*)d_in[2];
  const float* x_sin  = (const float*)d_in[3];
  const float* y_cos  = (const float*)d_in[4];
  const float* y_sin  = (const float*)d_in[5];
  const float* Wq     = (const float*)d_in[6];
  const float* bq     = (const float*)d_in[7];
  const float* Wk     = (const float*)d_in[8];
  const float* bk     = (const float*)d_in[9];
  const float* Wv     = (const float*)d_in[10];
  const float* bv     = (const float*)d_in[11];
  const float* Wo     = (const float*)d_in[12];
  const float* bo     = (const float*)d_in[13];
  const float* rmsq_w = (const float*)d_in[14];
  const float* rmsk_w = (const float*)d_in[15];
  const float* ln_w   = (const float*)d_in[16];
  const float* ln_b   = (const float*)d_in[17];

  char* ws = (char*)d_ws;
  // ws lifetimes (total 146,800,640 B):
  //  xb    [0, 33.5M)    : written prep, read gemm_dual(Q); ao aliases after.
  //  Wqb   [33.5, 41.9M) : written prep, read gemm_dual; kr aliases after.
  //  Wkb/Wvb [41.9,50.3M): written prep, read gemm_dual; vt aliases after.
  //  Wob   [50.3, 58.7M) : written prep, read final gemm_f32 (never clobbered).
  //  ynb   [58.7, 62.9M) : written prep, read gemm_dual(KV).
  //  qpre  [62.9, 96.5M) : written gemm_dual, read post(rmsq).
  //  kvpre [96.5,113.2M) : written gemm_dual, read post(rmsk, vtrans).
  //  qr    [113.2,146.8M): written post, read attn.
  unsigned short* xb    = (unsigned short*)(ws + 0);
  unsigned short* Wqb   = (unsigned short*)(ws + 33554432);
  unsigned short* Wkb   = (unsigned short*)(ws + 41943040);
  unsigned short* Wvb   = (unsigned short*)(ws + 46137344);
  unsigned short* Wob   = (unsigned short*)(ws + 50331648);
  unsigned short* ynb   = (unsigned short*)(ws + 58720256);
  unsigned short* qpre  = (unsigned short*)(ws + 62914560);
  unsigned short* kvpre = (unsigned short*)(ws + 96468992);
  unsigned short* qr    = (unsigned short*)(ws + 113246208);
  unsigned short* kr    = (unsigned short*)(ws + 33554432);   // over Wqb (dead)
  unsigned short* vt    = (unsigned short*)(ws + 41943040);   // over Wkb/Wvb (dead)
  unsigned short* ao    = xb;                                 // over xb (dead)
  (void)Wvb;

  const float qscale = 1.4426950408889634f * 0.08838834764831843f; // log2e/sqrt(128)

  prep_kernel<<<3584, 256, 0, stream>>>(y, ln_w, ln_b, ynb, x, Wq, Wk, Wv, Wo,
                                        xb, Wqb, Wkb, Wvb, Wob);
  gemm_dual<<<384, 512, 0, stream>>>(xb, Wqb, bq, qpre, ynb, Wkb, bk, bv, kvpre);
  post_kernel<<<10752, 256, 0, stream>>>(qpre, rmsq_w, x_cos, x_sin, qr,
                                         kvpre, rmsk_w, y_cos, y_sin, kr, vt, qscale);
  attn_kernel<<<512, 512, 0, stream>>>(qr, kr, vt, ao);
  gemm_f32<<<256, 512, 0, stream>>>(ao, Wob, bo, (float*)d_out, 8192, 2048, 2048);
}

// Round 14
// 303.323 us; speedup vs baseline: 1.3320x; 1.0003x over previous
//
#include <hip/hip_runtime.h>

// ---------------------------------------------------------------------------
// ConditionalCrossAttentionBlock: LN -> K/V proj -> RMS(Q proj) -> RoPE ->
// 16-head cross attention (LQ=4096, LKV=1024, Dh=128) -> O proj.
// R14: gemm_dual load-balanced — every block does its Q tile (32 units) then
// one KV K-half tile (8 units): uniform 40 units/block, no tail. KV written
// as two bf16 partials (no bias); post sums partials + bias in f32.
// Attn unchanged (R10 proven). 5 launches.
// ---------------------------------------------------------------------------

typedef __attribute__((ext_vector_type(8))) short    short8;
typedef __attribute__((ext_vector_type(8))) unsigned short ushort8;
typedef __attribute__((ext_vector_type(4))) unsigned short ushort4v;
typedef __attribute__((ext_vector_type(4))) float    f32x4;
typedef __attribute__((ext_vector_type(16))) float   f32x16;
typedef __attribute__((ext_vector_type(4))) unsigned int uint4v;

#define DEV __device__ __forceinline__

DEV unsigned short f2bf(float f) {
  unsigned int u = __builtin_bit_cast(unsigned int, f);
  u += 0x7FFFu + ((u >> 16) & 1u);        // RNE, inputs are finite
  return (unsigned short)(u >> 16);
}
DEV float bf2f(unsigned short h) {
  return __builtin_bit_cast(float, ((unsigned int)h) << 16);
}
DEV unsigned int cvtpk_bf16(float lo, float hi) {
  unsigned int r;
  asm("v_cvt_pk_bf16_f32 %0, %1, %2" : "=v"(r) : "v"(lo), "v"(hi));
  return r;
}
DEV short8 mk8(unsigned a, unsigned b, unsigned c, unsigned d) {
  uint4v t; t.x = a; t.y = b; t.z = c; t.w = d;
  return __builtin_bit_cast(short8, t);
}

DEV void gload_lds16(const void* g, void* l) {
  __builtin_amdgcn_global_load_lds(
      (const __attribute__((address_space(1))) void*)g,
      (__attribute__((address_space(3))) void*)l, 16, 0, 0);
}

// ---------------------------------------------------------------------------
// prep: blocks [0,2048) = LayerNorm rows; [2048,3584) = grid-stride f32->bf16
// over {x, Wq, Wk, Wv, Wo}.
// ---------------------------------------------------------------------------
__global__ __launch_bounds__(256) void prep_kernel(const float* __restrict__ y,
                                                   const float* __restrict__ lnw,
                                                   const float* __restrict__ lnb,
                                                   unsigned short* __restrict__ yn,
                                                   const float* __restrict__ x,
                                                   const float* __restrict__ Wq,
                                                   const float* __restrict__ Wk,
                                                   const float* __restrict__ Wv,
                                                   const float* __restrict__ Wo,
                                                   unsigned short* __restrict__ xb,
                                                   unsigned short* __restrict__ Wqb,
                                                   unsigned short* __restrict__ Wkb,
                                                   unsigned short* __restrict__ Wvb,
                                                   unsigned short* __restrict__ Wob) {
  const int t = threadIdx.x;
  if (blockIdx.x < 2048) {
    const int row = blockIdx.x;
    const float* yr = y + (size_t)row * 1024;
    float4 v = *(const float4*)(yr + t * 4);
    float s1 = v.x + v.y + v.z + v.w;
    float s2 = v.x * v.x + v.y * v.y + v.z * v.z + v.w * v.w;
#pragma unroll
    for (int m = 1; m < 64; m <<= 1) {
      s1 += __shfl_xor(s1, m);
      s2 += __shfl_xor(s2, m);
    }
    __shared__ float red[8];
    const int wave = t >> 6, lane = t & 63;
    if (lane == 0) { red[wave] = s1; red[4 + wave] = s2; }
    __syncthreads();
    s1 = red[0] + red[1] + red[2] + red[3];
    s2 = red[4] + red[5] + red[6] + red[7];
    const float mu = s1 * (1.0f / 1024.0f);
    const float var = s2 * (1.0f / 1024.0f) - mu * mu;
    const float rs = rsqrtf(var + 1e-6f);
    ushort4v o;
    o.x = f2bf((v.x - mu) * rs * lnw[t * 4 + 0] + lnb[t * 4 + 0]);
    o.y = f2bf((v.y - mu) * rs * lnw[t * 4 + 1] + lnb[t * 4 + 1]);
    o.z = f2bf((v.z - mu) * rs * lnw[t * 4 + 2] + lnb[t * 4 + 2]);
    o.w = f2bf((v.w - mu) * rs * lnw[t * 4 + 3] + lnb[t * 4 + 3]);
    *(ushort4v*)(yn + (size_t)row * 1024 + t * 4) = o;
    return;
  }
  const int nx = 4194304, nwq = 1048576, nwk = 524288, nwv = 524288;
  const int total = 7340032;
  int i = (blockIdx.x - 2048) * 256 + t;
  const int stride = 1536 * 256;
  for (; i < total; i += stride) {
    int j = i;
    const float* s; unsigned short* d;
    if (j < nx) { s = x; d = xb; }
    else if ((j -= nx) < nwq) { s = Wq; d = Wqb; }
    else if ((j -= nwq) < nwk) { s = Wk; d = Wkb; }
    else if ((j -= nwk) < nwv) { s = Wv; d = Wvb; }
    else { j -= nwv; s = Wo; d = Wob; }
    float4 v = *(const float4*)(s + (size_t)j * 4);
    ushort4v o;
    o.x = f2bf(v.x); o.y = f2bf(v.y); o.z = f2bf(v.z); o.w = f2bf(v.w);
    *(ushort4v*)(d + (size_t)j * 4) = o;
  }
}

// ---------------------------------------------------------------------------
// 256x256 8-phase pipelined GEMM body (T2+T3+T4+T5).
// C = A[M,K]@W[N,K]^T (+bias). ldRow = row stride in elements (>= K).
// EPI==0: bf16 out + bias; EPI==1: f32 out + bias; EPI==2: bf16 out, no bias.
// ---------------------------------------------------------------------------
template <int EPI>
DEV void gemm256_body(const unsigned short* __restrict__ A,
                      const unsigned short* __restrict__ W,
                      const float* __restrict__ bias0,
                      const float* __restrict__ bias1,
                      int nsplit, void* __restrict__ Cout,
                      int M, int N, int K, int ldRow,
                      int bidLocal, int nwg, char* ldsb, int tid) {
  const int wave = tid >> 6, lane = tid & 63;
  const int lg = lane >> 4, l15 = lane & 15;
  const int wm = wave >> 2, wn = wave & 3;

  const int wgid = (bidLocal & 7) * (nwg >> 3) + (bidLocal >> 3);
  const int nbn = N >> 8;
  const int m0 = (wgid / nbn) * 256;
  const int n0 = (wgid % nbn) * 256;

  const char* Ab = (const char*)A;
  const char* Wb = (const char*)W;
  const size_t ld = (size_t)ldRow * 2;
  const int NT = K >> 6;
  const int NI = NT >> 1;

  const int prow = tid >> 3;
  const int psw  = ((tid * 16) & 127) ^ ((prow & 7) << 4);
  const int pdst = tid * 16;
  const char* pAg = Ab + (size_t)(m0 + prow) * ld + psw;
  const char* pBg = Wb + (size_t)(n0 + prow) * ld + psw;

  f32x4 acc[8][4] = {};
  short8 af[4][2];
  short8 bf[4][2];

#define LDSB(BUF, SEG) (ldsb + ((BUF) * 4 + (SEG)) * 16384)

#define STG(BUF, HALF, ISB, TAU) do {                                         \
    const char* _g = ((ISB) ? pBg : pAg) + (size_t)(HALF) * 128 * ld +        \
                     (size_t)(TAU) * 128;                                     \
    char* _l = LDSB(BUF, (ISB) * 2 + (HALF));                                 \
    gload_lds16(_g, _l + pdst);                                               \
    gload_lds16(_g + 64 * ld, _l + pdst + 8192);                              \
  } while (0)

#define LDA(BUF, H) do {                                                      \
    const char* _b = LDSB(BUF, wm);                                           \
    _Pragma("unroll") for (int mfl = 0; mfl < 4; ++mfl) {                     \
      const int _r = (H) * 64 + mfl * 16 + l15;                               \
      _Pragma("unroll") for (int ks = 0; ks < 2; ++ks)                        \
        af[mfl][ks] = *(const short8*)(_b + _r * 128 +                        \
                        ((ks * 64 + lg * 16) ^ ((_r & 7) << 4)));             \
    }                                                                         \
  } while (0)

#define LDB(BUF, G) do {                                                      \
    const char* _b = LDSB(BUF, 2 + (wn >> 1));                                \
    _Pragma("unroll") for (int nfl = 0; nfl < 2; ++nfl) {                     \
      const int _r = (wn & 1) * 64 + (G) * 32 + nfl * 16 + l15;               \
      _Pragma("unroll") for (int ks = 0; ks < 2; ++ks)                        \
        bf[(G) * 2 + nfl][ks] = *(const short8*)(_b + _r * 128 +              \
                        ((ks * 64 + lg * 16) ^ ((_r & 7) << 4)));             \
    }                                                                         \
  } while (0)

#define MFMA_Q(H, G) do {                                                     \
    __builtin_amdgcn_s_setprio(1);                                            \
    _Pragma("unroll") for (int ks = 0; ks < 2; ++ks)                          \
    _Pragma("unroll") for (int mfl = 0; mfl < 4; ++mfl)                       \
    _Pragma("unroll") for (int nfl = 0; nfl < 2; ++nfl)                       \
      acc[(H) * 4 + mfl][(G) * 2 + nfl] =                                     \
        __builtin_amdgcn_mfma_f32_16x16x32_bf16(af[mfl][ks],                  \
            bf[(G) * 2 + nfl][ks], acc[(H) * 4 + mfl][(G) * 2 + nfl], 0,0,0); \
    __builtin_amdgcn_s_setprio(0);                                            \
  } while (0)

#define BAR() __builtin_amdgcn_s_barrier()
#define LGKM0() do { asm volatile("s_waitcnt lgkmcnt(0)" ::: "memory");       \
    __builtin_amdgcn_sched_barrier(0); } while (0)
#define VM4() asm volatile("s_waitcnt vmcnt(4)" ::: "memory")
#define VM0() asm volatile("s_waitcnt vmcnt(0)" ::: "memory")

  STG(0, 0, 0, 0); STG(0, 1, 0, 0); STG(0, 0, 1, 0); STG(0, 1, 1, 0);
  STG(1, 0, 1, 1); STG(1, 1, 1, 1);
  VM4(); BAR();

  for (int t = 0; t < NI - 1; ++t) {
    const int t2 = 2 * t;
    LDA(0, 0); LDB(0, 0); STG(1, 0, 0, t2 + 1);
    BAR(); LGKM0(); MFMA_Q(0, 0); BAR();
    LDB(0, 1); STG(1, 1, 0, t2 + 1);
    BAR(); LGKM0(); MFMA_Q(0, 1); BAR();
    LDA(0, 1); STG(0, 0, 1, t2 + 2);
    BAR(); LGKM0(); MFMA_Q(1, 1); BAR();
    STG(0, 1, 1, t2 + 2);
    BAR(); MFMA_Q(1, 0); VM4(); BAR();
    LDA(1, 0); LDB(1, 0); STG(0, 0, 0, t2 + 2);
    BAR(); LGKM0(); MFMA_Q(0, 0); BAR();
    LDB(1, 1); STG(0, 1, 0, t2 + 2);
    BAR(); LGKM0(); MFMA_Q(0, 1); BAR();
    LDA(1, 1); STG(1, 0, 1, t2 + 3);
    BAR(); LGKM0(); MFMA_Q(1, 1); BAR();
    STG(1, 1, 1, t2 + 3);
    BAR(); MFMA_Q(1, 0); VM4(); BAR();
  }

  LDA(0, 0); LDB(0, 0); STG(1, 0, 0, NT - 1);
  BAR(); LGKM0(); MFMA_Q(0, 0); BAR();
  LDB(0, 1); STG(1, 1, 0, NT - 1);
  BAR(); LGKM0(); MFMA_Q(0, 1); BAR();
  LDA(0, 1);
  BAR(); LGKM0(); MFMA_Q(1, 1); BAR();
  BAR(); MFMA_Q(1, 0); VM0(); BAR();
  LDA(1, 0); LDB(1, 0); LGKM0(); MFMA_Q(0, 0);
  LDB(1, 1); LGKM0(); MFMA_Q(0, 1);
  LDA(1, 1); LGKM0(); MFMA_Q(1, 1);
  MFMA_Q(1, 0);

#undef STG
#undef LDA
#undef LDB
#undef MFMA_Q
#undef BAR
#undef LGKM0
#undef VM4
#undef VM0
#undef LDSB

#pragma unroll
  for (int nf = 0; nf < 4; ++nf) {
    const int n = n0 + wn * 64 + nf * 16 + l15;
    float bv = 0.f;
    if constexpr (EPI != 2) bv = (n < nsplit) ? bias0[n] : bias1[n - nsplit];
#pragma unroll
    for (int mf = 0; mf < 8; ++mf) {
      const int mB = m0 + wm * 128 + mf * 16 + lg * 4;
#pragma unroll
      for (int r = 0; r < 4; ++r) {
        const float v = acc[mf][nf][r] + bv;
        if constexpr (EPI == 1)
          ((float*)Cout)[(size_t)(mB + r) * N + n] = v;
        else
          ((unsigned short*)Cout)[(size_t)(mB + r) * N + n] = f2bf(v);
      }
    }
  }
}

// Every block: Q tile (32 units) then one KV K-half tile (8 units). Grid 256.
__global__ __launch_bounds__(512, 2) void gemm_dual(const unsigned short* __restrict__ xb,
                                                    const unsigned short* __restrict__ Wqb,
                                                    const float* __restrict__ bq,
                                                    unsigned short* __restrict__ qpre,
                                                    const unsigned short* __restrict__ ynb,
                                                    const unsigned short* __restrict__ Wkb,
                                                    unsigned short* __restrict__ kvpA,
                                                    unsigned short* __restrict__ kvpB) {
  __shared__ __align__(16) char lds[2][4][16384];
  gemm256_body<0>(xb, Wqb, bq, bq, 2048, qpre, 8192, 2048, 2048, 2048,
                  blockIdx.x, 256, &lds[0][0][0], threadIdx.x);
  __syncthreads();   // all waves done with LDS before restaging
  const int kvt = blockIdx.x & 127, khalf = blockIdx.x >> 7;
  gemm256_body<2>(ynb + khalf * 512, Wkb + khalf * 512, nullptr, nullptr, 0,
                  khalf ? kvpB : kvpA, 2048, 4096, 512, 1024,
                  kvt, 128, &lds[0][0][0], threadIdx.x);
}

// O projection (f32 out).
__global__ __launch_bounds__(512, 2) void gemm_f32(const unsigned short* __restrict__ A,
                                                   const unsigned short* __restrict__ W,
                                                   const float* __restrict__ bias,
                                                   float* __restrict__ C,
                                                   int M, int N, int K) {
  __shared__ __align__(16) char lds[2][4][16384];
  gemm256_body<1>(A, W, bias, bias, N, C, M, N, K, K,
                  blockIdx.x, 256, &lds[0][0][0], threadIdx.x);
}

// ---------------------------------------------------------------------------
// post: blocks [0,8192) rmsrope_q; [8192,10240) rmsrope_k (sum partials +
// bias); [10240,10752) vtrans (sum partials + bias).
// ---------------------------------------------------------------------------
DEV void rmsrope2_body(const unsigned short* __restrict__ in,
                       const unsigned short* __restrict__ in2,
                       const float* __restrict__ bias,
                       const float* __restrict__ w,
                       const float* __restrict__ cs,
                       const float* __restrict__ sn,
                       unsigned short* __restrict__ out,
                       int L, int ldin, float scale, int row,
                       float* srow, float* red) {
  const int t = threadIdx.x;
  ushort8 v = *(const ushort8*)(in + (size_t)row * ldin + t * 8);
  float vals[8];
  if (in2) {
    ushort8 v2 = *(const ushort8*)(in2 + (size_t)row * ldin + t * 8);
#pragma unroll
    for (int j = 0; j < 8; ++j) vals[j] = bf2f(v[j]) + bf2f(v2[j]) + bias[t * 8 + j];
  } else {
#pragma unroll
    for (int j = 0; j < 8; ++j) vals[j] = bf2f(v[j]);
  }
  float ss = 0.f;
#pragma unroll
  for (int j = 0; j < 8; ++j) { ss += vals[j] * vals[j]; srow[t * 8 + j] = vals[j]; }
#pragma unroll
  for (int m = 1; m < 64; m <<= 1) ss += __shfl_xor(ss, m);
  const int wave = t >> 6, lane = t & 63;
  if (lane == 0) red[wave] = ss;
  __syncthreads();
  const float tot = red[0] + red[1] + red[2] + red[3];
  const float rms = rsqrtf(tot * (1.0f / 2048.0f) + 1e-6f);

  const int n0 = t * 8;
  const int d0 = n0 & 127;
  const int hh = n0 >> 7;
  const float sign = (d0 < 64) ? -1.0f : 1.0f;
  const float* cb = cs + (size_t)row * 128 + d0;
  const float* sb = sn + (size_t)row * 128 + d0;
  ushort8 ou;
#pragma unroll
  for (int j = 0; j < 8; ++j) {
    const float self = vals[j] * rms * w[n0 + j];
    const float part = srow[(n0 ^ 64) + j] * rms * w[(n0 ^ 64) + j];
    ou[j] = f2bf((self * cb[j] + sign * part * sb[j]) * scale);
  }
  const int b = row / L, l = row - (row / L) * L;
  *(ushort8*)(out + (((size_t)(b * 16 + hh)) * L + l) * 128 + d0) = ou;
}

DEV void vtrans2_body(const unsigned short* __restrict__ va,
                      const unsigned short* __restrict__ vb,
                      const float* __restrict__ bv,
                      unsigned short* __restrict__ vt, int ldv, int bid,
                      unsigned short (*lt)[130]) {
  const int kt = bid & 15, bh = bid >> 4;
  const int h = bh & 15, b = bh >> 4;
  const int t = threadIdx.x;
  const int i0 = t >> 4, c0 = (t & 15) * 8;
  const size_t sbase = ((size_t)(b * 1024 + kt * 64)) * ldv + h * 128;
#pragma unroll
  for (int ii = 0; ii < 4; ++ii) {
    const int i = i0 + ii * 16;
    ushort8 a = *(const ushort8*)(va + sbase + (size_t)i * ldv + c0);
    ushort8 bb = *(const ushort8*)(vb + sbase + (size_t)i * ldv + c0);
#pragma unroll
    for (int j = 0; j < 8; ++j)
      lt[i][c0 + j] = f2bf(bf2f(a[j]) + bf2f(bb[j]) + bv[h * 128 + c0 + j]);
  }
  __syncthreads();
  const int d0 = t >> 3, j0 = (t & 7) * 8;
  unsigned short* dst = vt + (size_t)bh * 128 * 1024 + kt * 64;
#pragma unroll
  for (int dd = 0; dd < 4; ++dd) {
    const int d = d0 + dd * 32;
    ushort8 o;
#pragma unroll
    for (int jj = 0; jj < 8; ++jj) o[jj] = lt[j0 + jj][d];
    *(ushort8*)(dst + (size_t)d * 1024 + j0) = o;
  }
}

__global__ __launch_bounds__(256) void post_kernel(const unsigned short* __restrict__ qpre,
                                                   const float* __restrict__ rmsq_w,
                                                   const float* __restrict__ x_cos,
                                                   const float* __restrict__ x_sin,
                                                   unsigned short* __restrict__ qr,
                                                   const unsigned short* __restrict__ kvpA,
                                                   const unsigned short* __restrict__ kvpB,
                                                   const float* __restrict__ bk,
                                                   const float* __restrict__ bv,
                                                   const float* __restrict__ rmsk_w,
                                                   const float* __restrict__ y_cos,
                                                   const float* __restrict__ y_sin,
                                                   unsigned short* __restrict__ kr,
                                                   unsigned short* __restrict__ vt,
                                                   float qscale) {
  __shared__ __align__(16) float srow[2048];
  __shared__ float red[4];
  __shared__ unsigned short lt[64][130];
  const int b = blockIdx.x;
  if (b < 8192) {
    rmsrope2_body(qpre, nullptr, nullptr, rmsq_w, x_cos, x_sin, qr,
                  4096, 2048, qscale, b, srow, red);
  } else if (b < 10240) {
    rmsrope2_body(kvpA, kvpB, bk, rmsk_w, y_cos, y_sin, kr,
                  1024, 4096, 1.0f, b - 8192, srow, red);
  } else {
    vtrans2_body(kvpA + 2048, kvpB + 2048, bv, vt, 4096, b - 10240, lt);
  }
}

// ---------------------------------------------------------------------------
// Flash cross-attention (R10, proven).
// ---------------------------------------------------------------------------
__global__ __launch_bounds__(512, 2) void attn_kernel(const unsigned short* __restrict__ q,
                                                      const unsigned short* __restrict__ k,
                                                      const unsigned short* __restrict__ vt,
                                                      unsigned short* __restrict__ ao) {
  __shared__ __align__(16) char sK[2][2][64 * 256];
  __shared__ __align__(16) char sV[2][2][64 * 256];

  const int bid0 = blockIdx.x;                      // 512 = 32 bh * 16 qtiles
  const int bid = (bid0 & 7) * 64 + (bid0 >> 3);
  const int qt = bid & 15, bh = bid >> 4;
  const int tid = threadIdx.x;
  const int wave = tid >> 6, lane = tid & 63;
  const int l31 = lane & 31, hi = lane >> 5;
  const bool hib = (hi != 0);

  const unsigned short* qbase = q + (((size_t)bh * 4096) + qt * 256 + wave * 32) * 128;
  const char* kbase = (const char*)(k + (size_t)bh * 1024 * 128);
  const char* vbase = (const char*)(vt + (size_t)bh * 128 * 1024);

  short8 qb[8];
#pragma unroll
  for (int step = 0; step < 8; ++step)
    qb[step] = *(const short8*)(qbase + (size_t)l31 * 128 + step * 16 + hi * 8);

  f32x16 o[4] = {};
  float lsum = 0.f;

#define STAGE_KV(BUF, KV0) do {                                              \
    _Pragma("unroll")                                                        \
    for (int sub = 0; sub < 2; ++sub) {                                      \
      _Pragma("unroll")                                                      \
      for (int i = 0; i < 2; ++i) {                                          \
        const int p = (i * 512 + tid) * 16;                                  \
        const int row = p >> 8;                                              \
        const int si = (p & 255) ^ ((row & 15) << 4);                        \
        gload_lds16(kbase + (size_t)((KV0) + sub * 64 + row) * 256 + si,     \
                    sK[BUF][sub] + p);                                       \
      }                                                                      \
      _Pragma("unroll")                                                      \
      for (int i = 0; i < 2; ++i) {                                          \
        const int p = (i * 512 + tid) * 16;                                  \
        const int row = p >> 8;                                              \
        const int si = (p & 255) ^ ((row & 15) << 4);                        \
        const int d = 2 * row + (si >> 7);                                   \
        gload_lds16(vbase + (size_t)d * 2048 + ((KV0) + sub * 64) * 2 +      \
                    (si & 127), sV[BUF][sub] + p);                           \
      }                                                                      \
    }                                                                        \
  } while (0)

#define QK(K, S0, S1) do {                                                   \
    const int ksw = (l31 & 15) << 4;                                         \
    _Pragma("unroll") for (int step = 0; step < 8; ++step) {                 \
      const int cb2 = step * 32 + hi * 16;                                   \
      short8 kf0 = *(const short8*)((K) + l31 * 256 + (cb2 ^ ksw));          \
      short8 kf1 = *(const short8*)((K) + (32 + l31) * 256 + (cb2 ^ ksw));   \
      S0 = __builtin_amdgcn_mfma_f32_32x32x16_bf16(kf0, qb[step], S0, 0,0,0);\
      S1 = __builtin_amdgcn_mfma_f32_32x32x16_bf16(kf1, qb[step], S1, 0,0,0);\
    }                                                                        \
  } while (0)

#define SOFTMAX_PV(V, SS, F) do {                                            \
    float p_[16];                                                            \
    _Pragma("unroll") for (int r = 0; r < 16; ++r) p_[r] = exp2f((SS)[r]);   \
    lsum += (((p_[0]+p_[1])+(p_[2]+p_[3])) + ((p_[4]+p_[5])+(p_[6]+p_[7])))  \
          + (((p_[8]+p_[9])+(p_[10]+p_[11])) + ((p_[12]+p_[13])+(p_[14]+p_[15])));\
    const unsigned w0 = cvtpk_bf16(p_[0], p_[1]),  w1 = cvtpk_bf16(p_[2], p_[3]), \
                   w2 = cvtpk_bf16(p_[4], p_[5]),  w3 = cvtpk_bf16(p_[6], p_[7]), \
                   w4 = cvtpk_bf16(p_[8], p_[9]),  w5 = cvtpk_bf16(p_[10], p_[11]),\
                   w6 = cvtpk_bf16(p_[12], p_[13]),w7 = cvtpk_bf16(p_[14], p_[15]);\
    const unsigned x0 = (unsigned)__shfl_xor((int)(hib ? w0 : w2), 32);      \
    const unsigned x1 = (unsigned)__shfl_xor((int)(hib ? w1 : w3), 32);      \
    const unsigned x2 = (unsigned)__shfl_xor((int)(hib ? w4 : w6), 32);      \
    const unsigned x3 = (unsigned)__shfl_xor((int)(hib ? w5 : w7), 32);      \
    const short8 fr0 = mk8(hib ? x0 : w0, hib ? x1 : w1,                     \
                           hib ? w2 : x0, hib ? w3 : x1);                    \
    const short8 fr1 = mk8(hib ? x2 : w4, hib ? x3 : w5,                     \
                           hib ? w6 : x2, hib ? w7 : x3);                    \
    _Pragma("unroll") for (int kstep = 0; kstep < 2; ++kstep) {              \
      const short8 pa = kstep ? fr1 : fr0;                                   \
      const int colb = (F) * 64 + kstep * 32 + hi * 16;                      \
      _Pragma("unroll") for (int dt = 0; dt < 4; ++dt) {                     \
        const int vrow = dt * 16 + (l31 >> 1);                               \
        const int inner = (l31 & 1) * 128 + colb;                            \
        short8 vf = *(const short8*)((V) + vrow * 256 +                      \
                                     (inner ^ ((vrow & 15) << 4)));          \
        o[dt] = __builtin_amdgcn_mfma_f32_32x32x16_bf16(pa, vf, o[dt], 0,0,0);\
      }                                                                      \
    }                                                                        \
  } while (0)

#define TILE(BUF) do {                                                       \
    f32x16 s0 = {}, s1 = {}, s2 = {}, s3 = {};                               \
    QK(sK[BUF][0], s0, s1);                                                  \
    QK(sK[BUF][1], s2, s3);                                                  \
    SOFTMAX_PV(sV[BUF][0], s0, 0);                                           \
    SOFTMAX_PV(sV[BUF][0], s1, 1);                                           \
    SOFTMAX_PV(sV[BUF][1], s2, 0);                                           \
    SOFTMAX_PV(sV[BUF][1], s3, 1);                                           \
  } while (0)

  STAGE_KV(0, 0);
  __syncthreads();

#pragma unroll 1
  for (int kt2 = 0; kt2 < 4; ++kt2) {
    STAGE_KV(1, (2 * kt2 + 1) * 128);
    TILE(0);
    __syncthreads();
    if (kt2 < 3) STAGE_KV(0, (2 * kt2 + 2) * 128);
    TILE(1);
    __syncthreads();
  }
#undef STAGE_KV
#undef QK
#undef SOFTMAX_PV
#undef TILE

  lsum += __shfl_xor(lsum, 32);
  const float linv = 1.0f / lsum;
  const int b = bh >> 4, h = bh & 15;
#pragma unroll
  for (int r = 0; r < 16; ++r) {
    const int crow = (r & 3) + 8 * (r >> 2) + 4 * hi;
    const float inv = __shfl(linv, crow);
    const int qg = qt * 256 + wave * 32 + crow;
    const size_t orow = ((size_t)b * 4096 + qg) * 2048 + h * 128;
#pragma unroll
    for (int dt = 0; dt < 4; ++dt)
      ao[orow + dt * 32 + l31] = f2bf(o[dt][r] * inv);
  }
}

// ---------------------------------------------------------------------------
extern "C" void kernel_launch(void* const* d_in, const int* in_sizes, int n_in,
                              void* d_out, int out_size, void* d_ws, size_t ws_size,
                              hipStream_t stream) {
  (void)in_sizes; (void)n_in; (void)out_size; (void)ws_size;
  const float* x      = (const float*)d_in[0];
  const float* y      = (const float*)d_in[1];
  const float* x_cos  = (const float*)d_in[2];
  const float* x_sin  = (const float*)d_in[3];
  const float* y_cos  = (const float*)d_in[4];
  const float* y_sin  = (const float*)d_in[5];
  const float* Wq     = (const float*)d_in[6];
  const float* bq     = (const float*)d_in[7];
  const float* Wk     = (const float*)d_in[8];
  const float* bk     = (const float*)d_in[9];
  const float* Wv     = (const float*)d_in[10];
  const float* bv     = (const float*)d_in[11];
  const float* Wo     = (const float*)d_in[12];
  const float* bo     = (const float*)d_in[13];
  const float* rmsq_w = (const float*)d_in[14];
  const float* rmsk_w = (const float*)d_in[15];
  const float* ln_w   = (const float*)d_in[16];
  const float* ln_b   = (const float*)d_in[17];

  char* ws = (char*)d_ws;
  // ws lifetimes (total 130,023,424 B):
  //  xb    [0, 33.5M)     : prep -> gemm_dual(Q);  qr overlays after.
  //  Wqb   [33.5, 41.9M)  : prep -> gemm_dual;     kr overlays after.
  //  Wkb/Wvb [41.9,50.3M) : prep -> gemm_dual;     vt overlays after.
  //  Wob   [50.3, 58.7M)  : prep -> final gemm_f32 (never clobbered).
  //  ynb   [58.7, 62.9M)  : prep -> gemm_dual(KV).
  //  qpre  [62.9, 96.5M)  : gemm_dual -> post;     ao overlays after.
  //  kvpA  [96.5,113.2M)  : gemm_dual -> post.
  //  kvpB  [113.2,130.0M) : gemm_dual -> post.
  unsigned short* xb    = (unsigned short*)(ws + 0);
  unsigned short* Wqb   = (unsigned short*)(ws + 33554432);
  unsigned short* Wkb   = (unsigned short*)(ws + 41943040);
  unsigned short* Wvb   = (unsigned short*)(ws + 46137344);
  unsigned short* Wob   = (unsigned short*)(ws + 50331648);
  unsigned short* ynb   = (unsigned short*)(ws + 58720256);
  unsigned short* qpre  = (unsigned short*)(ws + 62914560);
  unsigned short* kvpA  = (unsigned short*)(ws + 96468992);
  unsigned short* kvpB  = (unsigned short*)(ws + 113246208);
  unsigned short* qr    = xb;                                  // over xb (dead)
  unsigned short* kr    = Wqb;                                 // over Wqb (dead)
  unsigned short* vt    = Wkb;                                 // over Wkb/Wvb (dead)
  unsigned short* ao    = qpre;                                // over qpre (dead)
  (void)Wvb;

  const float qscale = 1.4426950408889634f * 0.08838834764831843f; // log2e/sqrt(128)

  prep_kernel<<<3584, 256, 0, stream>>>(y, ln_w, ln_b, ynb, x, Wq, Wk, Wv, Wo,
                                        xb, Wqb, Wkb, Wvb, Wob);
  gemm_dual<<<256, 512, 0, stream>>>(xb, Wqb, bq, qpre, ynb, Wkb, kvpA, kvpB);
  post_kernel<<<10752, 256, 0, stream>>>(qpre, rmsq_w, x_cos, x_sin, qr,
                                         kvpA, kvpB, bk, bv, rmsk_w,
                                         y_cos, y_sin, kr, vt, qscale);
  attn_kernel<<<512, 512, 0, stream>>>(qr, kr, vt, ao);
  gemm_f32<<<256, 512, 0, stream>>>(ao, Wob, bo, (float*)d_out, 8192, 2048, 2048);
}